// Round 7
// baseline (851.822 us; speedup 1.0000x reference)
//
#include <hip/hip_runtime.h>
#include <cstddef>

typedef _Float16 f16x4 __attribute__((ext_vector_type(4)));
typedef float f32x4 __attribute__((ext_vector_type(4)));

__device__ __forceinline__ f32x4 mfma16(f16x4 a, f16x4 b, f32x4 c) {
  return __builtin_amdgcn_mfma_f32_16x16x16f16(a, b, c, 0, 0, 0);
}

// Q is pre-scaled by 0.25 * log2(e) so softmax weights are exp2(score).
#define QSCALE (0.25f * 1.44269504f)
#define NSPLIT 8
#define NMC 4096
#define NPC 8192
#define EMC 65536
#define EPC 262144
#define NTOT (NMC + NPC)      // 12288 combined nodes (prot offset by NMC)
#define ETOT (EMC + EPC)      // 327680 combined edges

// ---------------------------------------------------------------------------
// init node embedding: out[n][o] = b[o] + sum_k in[n][k] * W[k][o]
// ---------------------------------------------------------------------------
__global__ __launch_bounds__(256) void init_embed_kernel(
    const float* __restrict__ in, const float* __restrict__ W,
    const float* __restrict__ b, float* __restrict__ out, int N, int Kin)
{
  int idx = blockIdx.x * 256 + threadIdx.x;
  if (idx >= N * 64) return;
  int n = idx >> 6, o = idx & 63;
  float acc = b[o];
  const float* row = in + (size_t)n * Kin;
  for (int k = 0; k < Kin; k++) acc += row[k] * W[k * 64 + o];
  out[idx] = acc;
}

// ===========================================================================
// CSR construction (once per call). Combined node space: mol [0,NM),
// prot [NM, NM+NP). All mol edges come first in slot space (mol dsts < NM),
// so slot < EM  <=>  mol edge.
// ===========================================================================
__global__ __launch_bounds__(256) void deg_hist_kernel(
    const int* __restrict__ eim, const int* __restrict__ eip, int* __restrict__ deg)
{
  int idx = blockIdx.x * 256 + threadIdx.x;
  if (idx >= ETOT) return;
  int dst = (idx < EMC) ? eim[EMC + idx] : (eip[EPC + (idx - EMC)] + NMC);
  atomicAdd(&deg[dst], 1);
}

// one block, 256 threads, 48 elems each: exclusive scan of deg -> rowStart,
// cursor (working copy); rowStart[NTOT] = total.
__global__ __launch_bounds__(256) void scan_kernel(
    const int* __restrict__ deg, int* __restrict__ rowStart, int* __restrict__ cursor)
{
  __shared__ int part[256];
  int t = threadIdx.x;
  int base = t * 48;
  int local[48];
  int s = 0;
  #pragma unroll
  for (int i = 0; i < 48; i++) { local[i] = s; s += deg[base + i]; }
  part[t] = s;
  __syncthreads();
  #pragma unroll
  for (int d = 1; d < 256; d <<= 1) {
    int v = (t >= d) ? part[t - d] : 0;
    __syncthreads();
    part[t] += v;
    __syncthreads();
  }
  int prefix = (t == 0) ? 0 : part[t - 1];
  #pragma unroll
  for (int i = 0; i < 48; i++) {
    int v = prefix + local[i];
    rowStart[base + i] = v;
    cursor[base + i] = v;
  }
  if (t == 255) rowStart[NTOT] = prefix + s;
}

__global__ __launch_bounds__(256) void fill_kernel(
    const int* __restrict__ eim, const int* __restrict__ eip,
    int* __restrict__ cursor, int* __restrict__ eidPerm, int* __restrict__ srcPerm)
{
  int idx = blockIdx.x * 256 + threadIdx.x;
  if (idx >= ETOT) return;
  int e, src, dst;
  if (idx < EMC) {
    e = idx; src = eim[e]; dst = eim[EMC + e];
  } else {
    e = idx - EMC; src = eip[e]; dst = eip[EPC + e] + NMC;
  }
  int slot = atomicAdd(&cursor[dst], 1);
  eidPerm[slot] = e;
  srcPerm[slot] = src;
}

// layer-invariant edge embedding, materialized in slot order (fp16).
// one wave per slot, lane = dim.
__global__ __launch_bounds__(256) void ea_perm_kernel(
    const int* __restrict__ eidPerm,
    const float* __restrict__ attrm, const float* __restrict__ Wem, const float* __restrict__ bem,
    const float* __restrict__ attrp, const float* __restrict__ Wep, const float* __restrict__ bep,
    _Float16* __restrict__ eaPerm)
{
  int wid = (blockIdx.x * 256 + threadIdx.x) >> 6;
  int lane = threadIdx.x & 63;
  if (wid >= ETOT) return;
  int e = eidPerm[wid];
  const float* arow;
  const float* We;
  const float* be;
  if (wid < EMC) { arow = attrm + (size_t)e * 10; We = Wem; be = bem; }
  else           { arow = attrp + (size_t)e * 10; We = Wep; be = bep; }
  float ea = be[lane];
  #pragma unroll
  for (int k = 0; k < 10; k++) ea += arow[k] * We[k * 64 + lane];
  eaPerm[(size_t)wid * 64 + lane] = (_Float16)ea;
}

// ---------------------------------------------------------------------------
// GINE aggregation via CSR gather: one wave per node, lane = dim.
// agg[n] = sum_i relu(x[src_i] + ea_i)  -- no atomics, no memset.
// ---------------------------------------------------------------------------
__global__ __launch_bounds__(256) void gine_gather_kernel(
    const float* __restrict__ xm, const float* __restrict__ xp,
    const int* __restrict__ rowStart, const int* __restrict__ srcPerm,
    const _Float16* __restrict__ eaPerm,
    float* __restrict__ aggm, float* __restrict__ aggp)
{
  int n = (blockIdx.x * 256 + threadIdx.x) >> 6;
  int lane = threadIdx.x & 63;
  if (n >= NTOT) return;
  const float* x;
  float* agg;
  int nl;
  if (n < NMC) { x = xm; agg = aggm; nl = n; }
  else         { x = xp; agg = aggp; nl = n - NMC; }
  int b0 = rowStart[n], b1 = rowStart[n + 1];
  float acc = 0.f;
  for (int i = b0; i < b1; i++) {
    int src = srcPerm[i];
    float m = x[(size_t)src * 64 + lane] + (float)eaPerm[(size_t)i * 64 + lane];
    acc += fmaxf(m, 0.f);
  }
  agg[(size_t)nl * 64 + lane] = acc;
}

// ---------------------------------------------------------------------------
// GINE node MLP for BOTH graphs: out = relu(relu((x+agg)@W1+B1)@W2+B2)
// blocks [0,64) mol, [64,192) prot.
// ---------------------------------------------------------------------------
__global__ __launch_bounds__(256) void gine_mlp_dual(
    const float* __restrict__ xm, const float* __restrict__ aggm,
    const float* __restrict__ W1m, const float* __restrict__ B1m,
    const float* __restrict__ W2m, const float* __restrict__ B2m,
    float* __restrict__ outm,
    const float* __restrict__ xp, const float* __restrict__ aggp,
    const float* __restrict__ W1p, const float* __restrict__ B1p,
    const float* __restrict__ W2p, const float* __restrict__ B2p,
    float* __restrict__ outp)
{
  __shared__ __align__(16) float sW1[64 * 64];
  __shared__ __align__(16) float sW2[64 * 64];
  __shared__ __align__(16) float sBuf[64 * 68];
  int t = threadIdx.x;
  int b = blockIdx.x;
  const float *x, *agg, *W1, *B1, *W2, *B2;
  float* out;
  int n0;
  if (b < 64) {
    x = xm; agg = aggm; W1 = W1m; B1 = B1m; W2 = W2m; B2 = B2m; out = outm; n0 = b * 64;
  } else {
    x = xp; agg = aggp; W1 = W1p; B1 = B1p; W2 = W2p; B2 = B2p; out = outp; n0 = (b - 64) * 64;
  }
  #pragma unroll
  for (int i = 0; i < 16; i++) { int f = t + i * 256; sW1[f] = W1[f]; sW2[f] = W2[f]; }
  #pragma unroll
  for (int i = 0; i < 16; i++) {
    int f = t + i * 256;
    size_t g = (size_t)n0 * 64 + f;
    sBuf[(f >> 6) * 68 + (f & 63)] = x[g] + agg[g];
  }
  __syncthreads();
  int n = t >> 2, kk = t & 3;
  float acc[16];
  #pragma unroll
  for (int j = 0; j < 16; j++) acc[j] = B1[kk * 16 + j];
  #pragma unroll
  for (int d = 0; d < 64; d++) {
    float xv = sBuf[n * 68 + d];
    const float* wrow = &sW1[d * 64 + kk * 16];
    #pragma unroll
    for (int j = 0; j < 16; j++) acc[j] += xv * wrow[j];
  }
  __syncthreads();
  #pragma unroll
  for (int j = 0; j < 16; j++) sBuf[n * 68 + kk * 16 + j] = fmaxf(acc[j], 0.f);
  __syncthreads();
  #pragma unroll
  for (int j = 0; j < 16; j++) acc[j] = B2[kk * 16 + j];
  #pragma unroll
  for (int d = 0; d < 64; d++) {
    float xv = sBuf[n * 68 + d];
    const float* wrow = &sW2[d * 64 + kk * 16];
    #pragma unroll
    for (int j = 0; j < 16; j++) acc[j] += xv * wrow[j];
  }
  float* op = out + (size_t)(n0 + n) * 64 + kk * 16;
  #pragma unroll
  for (int j = 0; j < 16; j++) op[j] = fmaxf(acc[j], 0.f);
}

// ---------------------------------------------------------------------------
// Fused QKV projection for BOTH graphs. Q,K -> fp16 [h][n][16] (Q scaled);
// V -> fp16 transposed [h][16][N]. blocks [0,64) mol, [64,192) prot.
// ---------------------------------------------------------------------------
__global__ __launch_bounds__(256) void proj_qkv_dual(
    const float* __restrict__ xm,
    const float* __restrict__ Wqm, const float* __restrict__ bqm,
    const float* __restrict__ Wkm, const float* __restrict__ bkm,
    const float* __restrict__ Wvm, const float* __restrict__ bvm,
    _Float16* __restrict__ Qom, _Float16* __restrict__ Kom, _Float16* __restrict__ Vtom,
    const float* __restrict__ xp,
    const float* __restrict__ Wqp, const float* __restrict__ bqp,
    const float* __restrict__ Wkp, const float* __restrict__ bkp,
    const float* __restrict__ Wvp, const float* __restrict__ bvp,
    _Float16* __restrict__ Qop, _Float16* __restrict__ Kop, _Float16* __restrict__ Vtop)
{
  __shared__ __align__(16) float sW[64 * 64];
  __shared__ __align__(16) float sIn[64 * 68];
  int t = threadIdx.x;
  int b = blockIdx.x;
  const float *xin, *Wq, *bq, *Wk, *bk, *Wv, *bv;
  _Float16 *Qo, *Ko, *Vto;
  int n0, N;
  if (b < 64) {
    xin = xm; Wq = Wqm; bq = bqm; Wk = Wkm; bk = bkm; Wv = Wvm; bv = bvm;
    Qo = Qom; Ko = Kom; Vto = Vtom; n0 = b * 64; N = NMC;
  } else {
    xin = xp; Wq = Wqp; bq = bqp; Wk = Wkp; bk = bkp; Wv = Wvp; bv = bvp;
    Qo = Qop; Ko = Kop; Vto = Vtop; n0 = (b - 64) * 64; N = NPC;
  }
  #pragma unroll
  for (int i = 0; i < 16; i++) {
    int f = t + i * 256;
    sIn[(f >> 6) * 68 + (f & 63)] = xin[(size_t)n0 * 64 + f];
  }
  int n = t >> 2, kk = t & 3;
  const float* Ws[3] = {Wq, Wk, Wv};
  const float* bs[3] = {bq, bk, bv};
  for (int p = 0; p < 3; p++) {
    __syncthreads();
    #pragma unroll
    for (int i = 0; i < 16; i++) { int f = t + i * 256; sW[f] = Ws[p][f]; }
    __syncthreads();
    float acc[16];
    #pragma unroll
    for (int j = 0; j < 16; j++) acc[j] = bs[p][kk * 16 + j];
    #pragma unroll
    for (int d = 0; d < 64; d++) {
      float xv = sIn[n * 68 + d];
      const float* wrow = &sW[d * 64 + kk * 16];
      #pragma unroll
      for (int j = 0; j < 16; j++) acc[j] += xv * wrow[j];
    }
    if (p == 2) {
      #pragma unroll
      for (int j = 0; j < 16; j++)
        Vto[((size_t)kk * 16 + j) * N + (n0 + n)] = (_Float16)acc[j];
    } else {
      float scale = (p == 0) ? QSCALE : 1.0f;
      _Float16 tmp[16];
      #pragma unroll
      for (int j = 0; j < 16; j++) tmp[j] = (_Float16)(acc[j] * scale);
      _Float16* base = (p == 0) ? Qo : Ko;
      float4* dst = (float4*)(base + ((size_t)kk * N + n0 + n) * 16);
      dst[0] = ((float4*)tmp)[0];
      dst[1] = ((float4*)tmp)[1];
    }
  }
}

// ---------------------------------------------------------------------------
// Key-split MFMA cross-attention, both directions in one launch.
// Grid (96, H, NSPLIT): bx<32 -> m2p qblock, else p2m qblock. 128 queries
// per block (8 q-chunks of 16 per wave); 4 waves own disjoint 64-key chunks
// of this block's key split. Unnormalized partial O/L to workspace.
// ---------------------------------------------------------------------------
__global__ __launch_bounds__(256, 4) void attn_split_kernel(
    const _Float16* __restrict__ Qm, const _Float16* __restrict__ Kp,
    const _Float16* __restrict__ Vtp, float* __restrict__ OPm, float* __restrict__ LPm,
    const _Float16* __restrict__ Qp, const _Float16* __restrict__ Km,
    const _Float16* __restrict__ Vtm, float* __restrict__ OPp, float* __restrict__ LPp)
{
  const int bx = blockIdx.x;
  const _Float16 *Q, *K, *Vt;
  float *Opart, *Lpart;
  int Nq, Nk, qb;
  if (bx < 32) { Q = Qm; K = Kp; Vt = Vtp; Opart = OPm; Lpart = LPm; Nq = NMC; Nk = NPC; qb = bx; }
  else         { Q = Qp; K = Km; Vt = Vtm; Opart = OPp; Lpart = LPp; Nq = NPC; Nk = NMC; qb = bx - 32; }
  const int h = blockIdx.y;
  const int split = blockIdx.z;
  const int Ks = Nk / NSPLIT;
  const int q0 = qb * 128;
  const int t = threadIdx.x;
  const int wave = t >> 6, lane = t & 63;
  const int l16 = lane & 15, quad = lane >> 4;

  f16x4 qf[8];
  #pragma unroll
  for (int g = 0; g < 8; g++)
    qf[g] = *(const f16x4*)(Q + ((size_t)h * Nq + q0 + g * 16 + l16) * 16 + quad * 4);
  const _Float16* Kh = K + (size_t)h * Nk * 16;
  const _Float16* Vh = Vt + ((size_t)h * 16 + l16) * Nk;

  f32x4 oacc[8];
  float lacc[8];
  #pragma unroll
  for (int g = 0; g < 8; g++) { oacc[g] = (f32x4){0.f,0.f,0.f,0.f}; lacc[g] = 0.f; }
  const f32x4 zero = {0.f, 0.f, 0.f, 0.f};

  const int kend = (split + 1) * Ks;
  for (int kb = split * Ks + wave * 64; kb < kend; kb += 256) {
    f16x4 kf[4], vf[4];
    #pragma unroll
    for (int c = 0; c < 4; c++) {
      kf[c] = *(const f16x4*)(Kh + (size_t)(kb + c * 16 + l16) * 16 + quad * 4);
      vf[c] = *(const f16x4*)(Vh + kb + c * 16 + quad * 4);
    }
    #pragma unroll
    for (int g = 0; g < 8; g++) {
      f32x4 s[4];
      #pragma unroll
      for (int c = 0; c < 4; c++) s[c] = mfma16(kf[c], qf[g], zero);
      f16x4 pf[4];
      #pragma unroll
      for (int c = 0; c < 4; c++)
        #pragma unroll
        for (int r = 0; r < 4; r++) {
          float p = exp2f(fminf(s[c][r], 14.f));
          lacc[g] += p;
          pf[c][r] = (_Float16)p;
        }
      #pragma unroll
      for (int c = 0; c < 4; c++) oacc[g] = mfma16(vf[c], pf[c], oacc[g]);
    }
  }

  // cross-wave combine, per q-chunk; store partials (no divide)
  __shared__ float sO[8][4][16][16];   // [chunk][wave][d][q]  32 KB
  __shared__ float sl[8][4][4][16];    // [chunk][wave][quad][q] 8 KB
  #pragma unroll
  for (int g = 0; g < 8; g++) {
    #pragma unroll
    for (int r = 0; r < 4; r++) sO[g][wave][quad * 4 + r][l16] = oacc[g][r];
    sl[g][wave][quad][l16] = lacc[g];
  }
  __syncthreads();
  {
    int q = t >> 4, d = t & 15;
    #pragma unroll
    for (int g = 0; g < 8; g++) {
      float O = 0.f, L = 0.f;
      #pragma unroll
      for (int w = 0; w < 4; w++) {
        O += sO[g][w][d][q];
        #pragma unroll
        for (int qd = 0; qd < 4; qd++) L += sl[g][w][qd][q];
      }
      size_t row = (size_t)split * Nq + q0 + g * 16 + q;
      Opart[row * 64 + h * 16 + d] = O;
      if (d == 0) Lpart[row * 4 + h] = L;
    }
  }
}

// ---------------------------------------------------------------------------
// Fused attn-split combine + LayerNorm(h + O/L) * g + b, BOTH graphs.
// ---------------------------------------------------------------------------
__global__ __launch_bounds__(256) void ln_combine_dual(
    const float* __restrict__ hm, const float* __restrict__ Om,
    const float* __restrict__ Lm, const float* __restrict__ gm,
    const float* __restrict__ bm, float* __restrict__ outm,
    const float* __restrict__ hp, const float* __restrict__ Op,
    const float* __restrict__ Lp, const float* __restrict__ gp,
    const float* __restrict__ bp, float* __restrict__ outp)
{
  int idx = blockIdx.x * 256 + threadIdx.x;
  const float *hb, *Opart, *Lpart, *g, *bb;
  float* out;
  int N;
  int totalM = NMC * 64;
  if (idx < totalM) {
    hb = hm; Opart = Om; Lpart = Lm; g = gm; bb = bm; out = outm; N = NMC;
  } else {
    idx -= totalM;
    if (idx >= NPC * 64) return;
    hb = hp; Opart = Op; Lpart = Lp; g = gp; bb = bp; out = outp; N = NPC;
  }
  int n = idx >> 6, d = idx & 63, h = d >> 4;
  float O = 0.f, L = 0.f;
  #pragma unroll
  for (int s = 0; s < NSPLIT; s++) {
    size_t row = (size_t)s * N + n;
    O += Opart[row * 64 + d];
    L += Lpart[row * 4 + h];
  }
  float v = hb[idx] + O / L;
  float sm = v;
  #pragma unroll
  for (int o = 1; o < 64; o <<= 1) sm += __shfl_xor(sm, o);
  float mu = sm * 0.015625f;
  float c = v - mu;
  float q = c * c;
  #pragma unroll
  for (int o = 1; o < 64; o <<= 1) q += __shfl_xor(q, o);
  float var = q * 0.015625f;
  out[idx] = c * rsqrtf(var + 1e-5f) * g[d] + bb[d];
}

// ---------------------------------------------------------------------------
// Pooling via sorted-run register accumulation.
// ---------------------------------------------------------------------------
__global__ __launch_bounds__(256) void pool_run_kernel(
    const float* __restrict__ xm, const int* __restrict__ bm,
    const float* __restrict__ xp, const int* __restrict__ bp,
    float* __restrict__ sums, float* __restrict__ cnt)
{
  int wid = (blockIdx.x * 256 + threadIdx.x) >> 6;
  int lane = threadIdx.x & 63;
  const float* x;
  const int* batch;
  int n0, colOff, cntOff;
  if (wid < 64) {
    x = xm; batch = bm; n0 = wid * 64; colOff = 0; cntOff = 0;
  } else {
    wid -= 64;
    if (wid >= 128) return;
    x = xp; batch = bp; n0 = wid * 64; colOff = 64; cntOff = 32;
  }
  float acc = 0.f;
  int cur = batch[n0];
  int run = 0;
  for (int i = 0; i < 64; i++) {
    int n = n0 + i;
    int s = batch[n];
    if (s != cur) {
      atomicAdd(&sums[cur * 128 + colOff + lane], acc);
      if (lane == 0) atomicAdd(&cnt[cntOff + cur], (float)run);
      acc = 0.f; run = 0; cur = s;
    }
    acc += x[(size_t)n * 64 + lane];
    run++;
  }
  atomicAdd(&sums[cur * 128 + colOff + lane], acc);
  if (lane == 0) atomicAdd(&cnt[cntOff + cur], (float)run);
}

// ---------------------------------------------------------------------------
// final head
// ---------------------------------------------------------------------------
__global__ __launch_bounds__(256) void final_kernel(
    const float* __restrict__ sums, const float* __restrict__ cnt,
    const float* __restrict__ fc1w, const float* __restrict__ fc1b,
    const float* __restrict__ fc2w, const float* __restrict__ fc2b,
    float* __restrict__ out)
{
  __shared__ float z[32 * 128];
  __shared__ float h1[32 * 64];
  int t = threadIdx.x;
  for (int f = t; f < 32 * 128; f += 256) {
    int s = f >> 7, j = f & 127;
    float c = cnt[(j >> 6) * 32 + s];
    z[f] = sums[f] / fmaxf(c, 1.f);
  }
  __syncthreads();
  for (int f = t; f < 32 * 64; f += 256) {
    int s = f >> 6, o = f & 63;
    float acc = fc1b[o];
    for (int j = 0; j < 128; j++) acc += z[s * 128 + j] * fc1w[j * 64 + o];
    h1[f] = fmaxf(acc, 0.f);
  }
  __syncthreads();
  if (t < 32) {
    float acc = fc2b[0];
    for (int o = 0; o < 64; o++) acc += h1[t * 64 + o] * fc2w[o];
    out[t] = 1.f / (1.f + __expf(-acc));
  }
}

// ---------------------------------------------------------------------------
extern "C" void kernel_launch(void* const* d_in, const int* in_sizes, int n_in,
                              void* d_out, int out_size, void* d_ws, size_t ws_size,
                              hipStream_t stream)
{
  (void)in_sizes; (void)n_in; (void)out_size; (void)ws_size;
  const float* mol_x          = (const float*)d_in[0];
  const float* prot_x         = (const float*)d_in[1];
  const float* mol_edge_attr  = (const float*)d_in[2];
  const float* prot_edge_attr = (const float*)d_in[3];
  const float* inm_w = (const float*)d_in[4];
  const float* inm_b = (const float*)d_in[5];
  const float* inp_w = (const float*)d_in[6];
  const float* inp_b = (const float*)d_in[7];
  const float* iem_w = (const float*)d_in[8];
  const float* iem_b = (const float*)d_in[9];
  const float* iep_w = (const float*)d_in[10];
  const float* iep_b = (const float*)d_in[11];
  const float* gm_w1 = (const float*)d_in[12];
  const float* gm_b1 = (const float*)d_in[13];
  const float* gm_w2 = (const float*)d_in[14];
  const float* gm_b2 = (const float*)d_in[15];
  const float* gp_w1 = (const float*)d_in[16];
  const float* gp_b1 = (const float*)d_in[17];
  const float* gp_w2 = (const float*)d_in[18];
  const float* gp_b2 = (const float*)d_in[19];
  const float* m2p_w = (const float*)d_in[20];
  const float* m2p_b = (const float*)d_in[21];
  const float* p2m_w = (const float*)d_in[22];
  const float* p2m_b = (const float*)d_in[23];
  const float* lnm_g = (const float*)d_in[24];
  const float* lnm_b = (const float*)d_in[25];
  const float* lnp_g = (const float*)d_in[26];
  const float* lnp_b = (const float*)d_in[27];
  const float* fc1_w = (const float*)d_in[28];
  const float* fc1_b = (const float*)d_in[29];
  const float* fc2_w = (const float*)d_in[30];
  const float* fc2_b = (const float*)d_in[31];
  const int* mol_ei     = (const int*)d_in[32];
  const int* prot_ei    = (const int*)d_in[33];
  const int* mol_batch  = (const int*)d_in[34];
  const int* prot_batch = (const int*)d_in[35];

  const int NM = NMC, NP = NPC;

  float* ws = (float*)d_ws;
  size_t off = 0;
  auto nxt  = [&](size_t n) { float* p = ws + off; off += n; return p; };
  auto nxtH = [&](size_t n) { _Float16* p = (_Float16*)(ws + off); off += (n + 1) / 2; return p; };
  auto nxtI = [&](size_t n) { int* p = (int*)(ws + off); off += n; return p; };
  float* x_mol    = nxt((size_t)NM * 64);
  float* x_prot   = nxt((size_t)NP * 64);
  float* agg_mol  = nxt((size_t)NM * 64);
  float* agg_prot = nxt((size_t)NP * 64);
  float* h_mol    = nxt((size_t)NM * 64);
  float* h_prot   = nxt((size_t)NP * 64);
  _Float16* Qm  = nxtH((size_t)NM * 64);
  _Float16* Km  = nxtH((size_t)NM * 64);
  _Float16* Vtm = nxtH((size_t)NM * 64);
  _Float16* Qp  = nxtH((size_t)NP * 64);
  _Float16* Kp  = nxtH((size_t)NP * 64);
  _Float16* Vtp = nxtH((size_t)NP * 64);
  float* OPm = nxt((size_t)NSPLIT * NM * 64);
  float* LPm = nxt((size_t)NSPLIT * NM * 4);
  float* OPp = nxt((size_t)NSPLIT * NP * 64);
  float* LPp = nxt((size_t)NSPLIT * NP * 4);
  float* pool = nxt(32 * 128);
  float* cnt  = nxt(64);
  int* deg      = nxtI(NTOT);        // zeroed below
  int* rowStart = nxtI(NTOT + 1);
  int* cursor   = nxtI(NTOT);
  int* eidPerm  = nxtI(ETOT);
  int* srcPerm  = nxtI(ETOT);
  _Float16* eaPerm = nxtH((size_t)ETOT * 64);

  // ---- CSR + edge-embedding setup (once per call) ----
  (void)hipMemsetAsync(deg, 0, NTOT * 4, stream);
  deg_hist_kernel<<<(ETOT + 255) / 256, 256, 0, stream>>>(mol_ei, prot_ei, deg);
  scan_kernel<<<1, 256, 0, stream>>>(deg, rowStart, cursor);
  fill_kernel<<<(ETOT + 255) / 256, 256, 0, stream>>>(mol_ei, prot_ei, cursor, eidPerm, srcPerm);
  ea_perm_kernel<<<ETOT / 4, 256, 0, stream>>>(eidPerm,
      mol_edge_attr, iem_w, iem_b, prot_edge_attr, iep_w, iep_b, eaPerm);

  init_embed_kernel<<<NM * 64 / 256, 256, 0, stream>>>(mol_x, inm_w, inm_b, x_mol, NM, 11);
  init_embed_kernel<<<NP * 64 / 256, 256, 0, stream>>>(prot_x, inp_w, inp_b, x_prot, NP, 15);

  for (int l = 0; l < 3; l++) {
    gine_gather_kernel<<<NTOT / 4, 256, 0, stream>>>(x_mol, x_prot, rowStart, srcPerm,
                                                     eaPerm, agg_mol, agg_prot);
    gine_mlp_dual<<<192, 256, 0, stream>>>(
        x_mol, agg_mol, gm_w1 + l * 4096, gm_b1 + l * 64, gm_w2 + l * 4096, gm_b2 + l * 64, h_mol,
        x_prot, agg_prot, gp_w1 + l * 4096, gp_b1 + l * 64, gp_w2 + l * 4096, gp_b2 + l * 64, h_prot);
    // m2p: Q=mol (m2p W0), K/V=prot (m2p W1,W2); p2m: Q=prot (p2m W0), K/V=mol (p2m W1,W2)
    proj_qkv_dual<<<192, 256, 0, stream>>>(
        h_mol,
        m2p_w + (l * 3 + 0) * 4096, m2p_b + (l * 3 + 0) * 64,
        p2m_w + (l * 3 + 1) * 4096, p2m_b + (l * 3 + 1) * 64,
        p2m_w + (l * 3 + 2) * 4096, p2m_b + (l * 3 + 2) * 64,
        Qm, Km, Vtm,
        h_prot,
        p2m_w + (l * 3 + 0) * 4096, p2m_b + (l * 3 + 0) * 64,
        m2p_w + (l * 3 + 1) * 4096, m2p_b + (l * 3 + 1) * 64,
        m2p_w + (l * 3 + 2) * 4096, m2p_b + (l * 3 + 2) * 64,
        Qp, Kp, Vtp);
    attn_split_kernel<<<dim3(96, 4, NSPLIT), 256, 0, stream>>>(
        Qm, Kp, Vtp, OPm, LPm, Qp, Km, Vtm, OPp, LPp);
    ln_combine_dual<<<(NM + NP) * 64 / 256, 256, 0, stream>>>(
        h_mol, OPm, LPm, lnm_g + l * 64, lnm_b + l * 64, x_mol,
        h_prot, OPp, LPp, lnp_g + l * 64, lnp_b + l * 64, x_prot);
  }

  (void)hipMemsetAsync(pool, 0, (32 * 128 + 64) * 4, stream);
  pool_run_kernel<<<48, 256, 0, stream>>>(x_mol, mol_batch, x_prot, prot_batch, pool, cnt);
  final_kernel<<<1, 256, 0, stream>>>(pool, cnt, fc1_w, fc1_b, fc2_w, fc2_b, (float*)d_out);
}

// Round 9
// 778.794 us; speedup vs baseline: 1.0938x; 1.0938x over previous
//
#include <hip/hip_runtime.h>
#include <cstddef>

typedef _Float16 f16x4 __attribute__((ext_vector_type(4)));
typedef __fp16 h16x2 __attribute__((ext_vector_type(2)));
typedef float f32x4 __attribute__((ext_vector_type(4)));

__device__ __forceinline__ f32x4 mfma16(f16x4 a, f16x4 b, f32x4 c) {
  return __builtin_amdgcn_mfma_f32_16x16x16f16(a, b, c, 0, 0, 0);
}

// Q is pre-scaled by 0.25 * log2(e) so softmax weights are exp2(score).
#define QSCALE (0.25f * 1.44269504f)
#define NSPLIT 8
#define NMC 4096
#define NPC 8192
#define EMC 65536
#define EPC 262144
#define NTOT (NMC + NPC)      // 12288 combined nodes (prot offset by NMC)
#define ETOT (EMC + EPC)      // 327680 combined edges

// ---------------------------------------------------------------------------
// init node embedding: out[n][o] = b[o] + sum_k in[n][k] * W[k][o]
// ---------------------------------------------------------------------------
__global__ __launch_bounds__(256) void init_embed_kernel(
    const float* __restrict__ in, const float* __restrict__ W,
    const float* __restrict__ b, float* __restrict__ out, int N, int Kin)
{
  int idx = blockIdx.x * 256 + threadIdx.x;
  if (idx >= N * 64) return;
  int n = idx >> 6, o = idx & 63;
  float acc = b[o];
  const float* row = in + (size_t)n * Kin;
  for (int k = 0; k < Kin; k++) acc += row[k] * W[k * 64 + o];
  out[idx] = acc;
}

// ===========================================================================
// CSR construction (once per call). Combined node space: mol [0,NM),
// prot [NM, NM+NP). All mol edges come first in slot space (mol dsts < NM),
// so slot < EM  <=>  mol edge.
// ===========================================================================
__global__ __launch_bounds__(256) void deg_hist_kernel(
    const int* __restrict__ eim, const int* __restrict__ eip, int* __restrict__ deg)
{
  int idx = blockIdx.x * 256 + threadIdx.x;
  if (idx >= ETOT) return;
  int dst = (idx < EMC) ? eim[EMC + idx] : (eip[EPC + (idx - EMC)] + NMC);
  atomicAdd(&deg[dst], 1);
}

// one block, 256 threads, 48 elems each: exclusive scan of deg -> rowStart,
// cursor (working copy); rowStart[NTOT] = total.
__global__ __launch_bounds__(256) void scan_kernel(
    const int* __restrict__ deg, int* __restrict__ rowStart, int* __restrict__ cursor)
{
  __shared__ int part[256];
  int t = threadIdx.x;
  int base = t * 48;
  int local[48];
  int s = 0;
  #pragma unroll
  for (int i = 0; i < 48; i++) { local[i] = s; s += deg[base + i]; }
  part[t] = s;
  __syncthreads();
  #pragma unroll
  for (int d = 1; d < 256; d <<= 1) {
    int v = (t >= d) ? part[t - d] : 0;
    __syncthreads();
    part[t] += v;
    __syncthreads();
  }
  int prefix = (t == 0) ? 0 : part[t - 1];
  #pragma unroll
  for (int i = 0; i < 48; i++) {
    int v = prefix + local[i];
    rowStart[base + i] = v;
    cursor[base + i] = v;
  }
  if (t == 255) rowStart[NTOT] = prefix + s;
}

__global__ __launch_bounds__(256) void fill_kernel(
    const int* __restrict__ eim, const int* __restrict__ eip,
    int* __restrict__ cursor, int* __restrict__ eidPerm, int* __restrict__ srcPerm)
{
  int idx = blockIdx.x * 256 + threadIdx.x;
  if (idx >= ETOT) return;
  int e, src, dst;
  if (idx < EMC) {
    e = idx; src = eim[e]; dst = eim[EMC + e];
  } else {
    e = idx - EMC; src = eip[e]; dst = eip[EPC + e] + NMC;
  }
  int slot = atomicAdd(&cursor[dst], 1);
  eidPerm[slot] = e;
  srcPerm[slot] = src;
}

// layer-invariant edge embedding, materialized in slot order (fp16).
// one wave per slot, lane = dim.
__global__ __launch_bounds__(256) void ea_perm_kernel(
    const int* __restrict__ eidPerm,
    const float* __restrict__ attrm, const float* __restrict__ Wem, const float* __restrict__ bem,
    const float* __restrict__ attrp, const float* __restrict__ Wep, const float* __restrict__ bep,
    _Float16* __restrict__ eaPerm)
{
  int wid = (blockIdx.x * 256 + threadIdx.x) >> 6;
  int lane = threadIdx.x & 63;
  if (wid >= ETOT) return;
  int e = eidPerm[wid];
  const float* arow;
  const float* We;
  const float* be;
  if (wid < EMC) { arow = attrm + (size_t)e * 10; We = Wem; be = bem; }
  else           { arow = attrp + (size_t)e * 10; We = Wep; be = bep; }
  float ea = be[lane];
  #pragma unroll
  for (int k = 0; k < 10; k++) ea += arow[k] * We[k * 64 + lane];
  eaPerm[(size_t)wid * 64 + lane] = (_Float16)ea;
}

// ---------------------------------------------------------------------------
// GINE aggregation via CSR gather: one wave per node, lane = dim.
// agg[n] = sum_i relu(x[src_i] + ea_i)  -- no atomics, no memset.
// 4x unrolled: batch the index/ea/x loads to pipeline latency.
// ---------------------------------------------------------------------------
__global__ __launch_bounds__(256) void gine_gather_kernel(
    const float* __restrict__ xm, const float* __restrict__ xp,
    const int* __restrict__ rowStart, const int* __restrict__ srcPerm,
    const _Float16* __restrict__ eaPerm,
    float* __restrict__ aggm, float* __restrict__ aggp)
{
  int n = (blockIdx.x * 256 + threadIdx.x) >> 6;
  int lane = threadIdx.x & 63;
  if (n >= NTOT) return;
  const float* x;
  float* agg;
  int nl;
  if (n < NMC) { x = xm; agg = aggm; nl = n; }
  else         { x = xp; agg = aggp; nl = n - NMC; }
  int b0 = rowStart[n], b1 = rowStart[n + 1];
  float acc = 0.f;
  int i = b0;
  for (; i + 3 < b1; i += 4) {
    int s0 = srcPerm[i], s1 = srcPerm[i + 1], s2 = srcPerm[i + 2], s3 = srcPerm[i + 3];
    float e0 = (float)eaPerm[(size_t)i * 64 + lane];
    float e1 = (float)eaPerm[(size_t)(i + 1) * 64 + lane];
    float e2 = (float)eaPerm[(size_t)(i + 2) * 64 + lane];
    float e3 = (float)eaPerm[(size_t)(i + 3) * 64 + lane];
    float x0 = x[(size_t)s0 * 64 + lane];
    float x1 = x[(size_t)s1 * 64 + lane];
    float x2 = x[(size_t)s2 * 64 + lane];
    float x3 = x[(size_t)s3 * 64 + lane];
    acc += fmaxf(x0 + e0, 0.f) + fmaxf(x1 + e1, 0.f)
         + fmaxf(x2 + e2, 0.f) + fmaxf(x3 + e3, 0.f);
  }
  for (; i < b1; i++) {
    int src = srcPerm[i];
    float m = x[(size_t)src * 64 + lane] + (float)eaPerm[(size_t)i * 64 + lane];
    acc += fmaxf(m, 0.f);
  }
  agg[(size_t)nl * 64 + lane] = acc;
}

// ---------------------------------------------------------------------------
// GINE node MLP for BOTH graphs: out = relu(relu((x+agg)@W1+B1)@W2+B2)
// blocks [0,64) mol, [64,192) prot.
// ---------------------------------------------------------------------------
__global__ __launch_bounds__(256) void gine_mlp_dual(
    const float* __restrict__ xm, const float* __restrict__ aggm,
    const float* __restrict__ W1m, const float* __restrict__ B1m,
    const float* __restrict__ W2m, const float* __restrict__ B2m,
    float* __restrict__ outm,
    const float* __restrict__ xp, const float* __restrict__ aggp,
    const float* __restrict__ W1p, const float* __restrict__ B1p,
    const float* __restrict__ W2p, const float* __restrict__ B2p,
    float* __restrict__ outp)
{
  __shared__ __align__(16) float sW1[64 * 64];
  __shared__ __align__(16) float sW2[64 * 64];
  __shared__ __align__(16) float sBuf[64 * 68];
  int t = threadIdx.x;
  int b = blockIdx.x;
  const float *x, *agg, *W1, *B1, *W2, *B2;
  float* out;
  int n0;
  if (b < 64) {
    x = xm; agg = aggm; W1 = W1m; B1 = B1m; W2 = W2m; B2 = B2m; out = outm; n0 = b * 64;
  } else {
    x = xp; agg = aggp; W1 = W1p; B1 = B1p; W2 = W2p; B2 = B2p; out = outp; n0 = (b - 64) * 64;
  }
  #pragma unroll
  for (int i = 0; i < 16; i++) { int f = t + i * 256; sW1[f] = W1[f]; sW2[f] = W2[f]; }
  #pragma unroll
  for (int i = 0; i < 16; i++) {
    int f = t + i * 256;
    size_t g = (size_t)n0 * 64 + f;
    sBuf[(f >> 6) * 68 + (f & 63)] = x[g] + agg[g];
  }
  __syncthreads();
  int n = t >> 2, kk = t & 3;
  float acc[16];
  #pragma unroll
  for (int j = 0; j < 16; j++) acc[j] = B1[kk * 16 + j];
  #pragma unroll
  for (int d = 0; d < 64; d++) {
    float xv = sBuf[n * 68 + d];
    const float* wrow = &sW1[d * 64 + kk * 16];
    #pragma unroll
    for (int j = 0; j < 16; j++) acc[j] += xv * wrow[j];
  }
  __syncthreads();
  #pragma unroll
  for (int j = 0; j < 16; j++) sBuf[n * 68 + kk * 16 + j] = fmaxf(acc[j], 0.f);
  __syncthreads();
  #pragma unroll
  for (int j = 0; j < 16; j++) acc[j] = B2[kk * 16 + j];
  #pragma unroll
  for (int d = 0; d < 64; d++) {
    float xv = sBuf[n * 68 + d];
    const float* wrow = &sW2[d * 64 + kk * 16];
    #pragma unroll
    for (int j = 0; j < 16; j++) acc[j] += xv * wrow[j];
  }
  float* op = out + (size_t)(n0 + n) * 64 + kk * 16;
  #pragma unroll
  for (int j = 0; j < 16; j++) op[j] = fmaxf(acc[j], 0.f);
}

// ---------------------------------------------------------------------------
// Fused QKV projection for BOTH graphs. Q,K -> fp16 [h][n][16] (Q scaled);
// V -> fp16 transposed [h][16][N]. blocks [0,64) mol, [64,192) prot.
// ---------------------------------------------------------------------------
__global__ __launch_bounds__(256) void proj_qkv_dual(
    const float* __restrict__ xm,
    const float* __restrict__ Wqm, const float* __restrict__ bqm,
    const float* __restrict__ Wkm, const float* __restrict__ bkm,
    const float* __restrict__ Wvm, const float* __restrict__ bvm,
    _Float16* __restrict__ Qom, _Float16* __restrict__ Kom, _Float16* __restrict__ Vtom,
    const float* __restrict__ xp,
    const float* __restrict__ Wqp, const float* __restrict__ bqp,
    const float* __restrict__ Wkp, const float* __restrict__ bkp,
    const float* __restrict__ Wvp, const float* __restrict__ bvp,
    _Float16* __restrict__ Qop, _Float16* __restrict__ Kop, _Float16* __restrict__ Vtop)
{
  __shared__ __align__(16) float sW[64 * 64];
  __shared__ __align__(16) float sIn[64 * 68];
  int t = threadIdx.x;
  int b = blockIdx.x;
  const float *xin, *Wq, *bq, *Wk, *bk, *Wv, *bv;
  _Float16 *Qo, *Ko, *Vto;
  int n0, N;
  if (b < 64) {
    xin = xm; Wq = Wqm; bq = bqm; Wk = Wkm; bk = bkm; Wv = Wvm; bv = bvm;
    Qo = Qom; Ko = Kom; Vto = Vtom; n0 = b * 64; N = NMC;
  } else {
    xin = xp; Wq = Wqp; bq = bqp; Wk = Wkp; bk = bkp; Wv = Wvp; bv = bvp;
    Qo = Qop; Ko = Kop; Vto = Vtop; n0 = (b - 64) * 64; N = NPC;
  }
  #pragma unroll
  for (int i = 0; i < 16; i++) {
    int f = t + i * 256;
    sIn[(f >> 6) * 68 + (f & 63)] = xin[(size_t)n0 * 64 + f];
  }
  int n = t >> 2, kk = t & 3;
  const float* Ws[3] = {Wq, Wk, Wv};
  const float* bs[3] = {bq, bk, bv};
  for (int p = 0; p < 3; p++) {
    __syncthreads();
    #pragma unroll
    for (int i = 0; i < 16; i++) { int f = t + i * 256; sW[f] = Ws[p][f]; }
    __syncthreads();
    float acc[16];
    #pragma unroll
    for (int j = 0; j < 16; j++) acc[j] = bs[p][kk * 16 + j];
    #pragma unroll
    for (int d = 0; d < 64; d++) {
      float xv = sIn[n * 68 + d];
      const float* wrow = &sW[d * 64 + kk * 16];
      #pragma unroll
      for (int j = 0; j < 16; j++) acc[j] += xv * wrow[j];
    }
    if (p == 2) {
      #pragma unroll
      for (int j = 0; j < 16; j++)
        Vto[((size_t)kk * 16 + j) * N + (n0 + n)] = (_Float16)acc[j];
    } else {
      float scale = (p == 0) ? QSCALE : 1.0f;
      _Float16 tmp[16];
      #pragma unroll
      for (int j = 0; j < 16; j++) tmp[j] = (_Float16)(acc[j] * scale);
      _Float16* base = (p == 0) ? Qo : Ko;
      float4* dst = (float4*)(base + ((size_t)kk * N + n0 + n) * 16);
      dst[0] = ((float4*)tmp)[0];
      dst[1] = ((float4*)tmp)[1];
    }
  }
}

// ---------------------------------------------------------------------------
// Key-split MFMA cross-attention, both directions in one launch.
// Grid (96, H, NSPLIT): bx<32 -> m2p qblock, else p2m qblock. 128 queries
// per block; 4 waves own disjoint 64-key chunks of this block's key split.
// Softmax weights: exp2(score) clamped at 14; f16 conversion via packed
// cvt_pkrtz; L accumulated with packed v_dot2 on the same f16 values.
// Two-pass LDS combine (padded, ~20 KB) -> unnormalized partial O/L.
// ---------------------------------------------------------------------------
__global__ __launch_bounds__(256, 4) void attn_split_kernel(
    const _Float16* __restrict__ Qm, const _Float16* __restrict__ Kp,
    const _Float16* __restrict__ Vtp, float* __restrict__ OPm, float* __restrict__ LPm,
    const _Float16* __restrict__ Qp, const _Float16* __restrict__ Km,
    const _Float16* __restrict__ Vtm, float* __restrict__ OPp, float* __restrict__ LPp)
{
  const int bx = blockIdx.x;
  const _Float16 *Q, *K, *Vt;
  float *Opart, *Lpart;
  int Nq, Nk, qb;
  if (bx < 32) { Q = Qm; K = Kp; Vt = Vtp; Opart = OPm; Lpart = LPm; Nq = NMC; Nk = NPC; qb = bx; }
  else         { Q = Qp; K = Km; Vt = Vtm; Opart = OPp; Lpart = LPp; Nq = NPC; Nk = NMC; qb = bx - 32; }
  const int h = blockIdx.y;
  const int split = blockIdx.z;
  const int Ks = Nk / NSPLIT;
  const int q0 = qb * 128;
  const int t = threadIdx.x;
  const int wave = t >> 6, lane = t & 63;
  const int l16 = lane & 15, quad = lane >> 4;

  f16x4 qf[8];
  #pragma unroll
  for (int g = 0; g < 8; g++)
    qf[g] = *(const f16x4*)(Q + ((size_t)h * Nq + q0 + g * 16 + l16) * 16 + quad * 4);
  const _Float16* Kh = K + (size_t)h * Nk * 16;
  const _Float16* Vh = Vt + ((size_t)h * 16 + l16) * Nk;

  f32x4 oacc[8];
  float lacc[8];
  #pragma unroll
  for (int g = 0; g < 8; g++) { oacc[g] = (f32x4){0.f,0.f,0.f,0.f}; lacc[g] = 0.f; }
  const f32x4 zero = {0.f, 0.f, 0.f, 0.f};
  const h16x2 ones2 = {(__fp16)1.f, (__fp16)1.f};

  union PF { f16x4 v4; h16x2 h2[2]; };

  const int kend = (split + 1) * Ks;
  for (int kb = split * Ks + wave * 64; kb < kend; kb += 256) {
    f16x4 kf[4], vf[4];
    #pragma unroll
    for (int c = 0; c < 4; c++) {
      kf[c] = *(const f16x4*)(Kh + (size_t)(kb + c * 16 + l16) * 16 + quad * 4);
      vf[c] = *(const f16x4*)(Vh + kb + c * 16 + quad * 4);
    }
    #pragma unroll
    for (int g = 0; g < 8; g++) {
      f32x4 s[4];
      #pragma unroll
      for (int c = 0; c < 4; c++) s[c] = mfma16(kf[c], qf[g], zero);
      f16x4 pf[4];
      #pragma unroll
      for (int c = 0; c < 4; c++) {
        float p0 = exp2f(fminf(s[c][0], 14.f));
        float p1 = exp2f(fminf(s[c][1], 14.f));
        float p2 = exp2f(fminf(s[c][2], 14.f));
        float p3 = exp2f(fminf(s[c][3], 14.f));
        PF u;
        u.h2[0] = __builtin_amdgcn_cvt_pkrtz(p0, p1);
        u.h2[1] = __builtin_amdgcn_cvt_pkrtz(p2, p3);
        pf[c] = u.v4;
        lacc[g] = __builtin_amdgcn_fdot2(u.h2[0], ones2, lacc[g], false);
        lacc[g] = __builtin_amdgcn_fdot2(u.h2[1], ones2, lacc[g], false);
      }
      #pragma unroll
      for (int c = 0; c < 4; c++) oacc[g] = mfma16(vf[c], pf[c], oacc[g]);
    }
  }

  // quad-reduce L within wave: lane l16 then holds L[q] for this wave
  #pragma unroll
  for (int g = 0; g < 8; g++) {
    lacc[g] += __shfl_xor(lacc[g], 16);
    lacc[g] += __shfl_xor(lacc[g], 32);
  }

  // two-pass cross-wave combine (reuse padded sO; ~20 KB total)
  __shared__ float sO[4][4][16][17];   // [gg][wave][d][q(+pad)]
  __shared__ float sLw[8][4][16];      // [g][wave][q]
  if (quad == 0) {
    #pragma unroll
    for (int g = 0; g < 8; g++) sLw[g][wave][l16] = lacc[g];
  }
  int q = t >> 4, d = t & 15;
  #pragma unroll
  for (int pass = 0; pass < 2; pass++) {
    __syncthreads();
    #pragma unroll
    for (int gg = 0; gg < 4; gg++) {
      int g = pass * 4 + gg;
      #pragma unroll
      for (int r = 0; r < 4; r++) sO[gg][wave][quad * 4 + r][l16] = oacc[g][r];
    }
    __syncthreads();
    #pragma unroll
    for (int gg = 0; gg < 4; gg++) {
      int g = pass * 4 + gg;
      float O = 0.f;
      #pragma unroll
      for (int w = 0; w < 4; w++) O += sO[gg][w][d][q];
      size_t row = (size_t)split * Nq + q0 + g * 16 + q;
      Opart[row * 64 + h * 16 + d] = O;
      if (d == 0) {
        float L = sLw[g][0][q] + sLw[g][1][q] + sLw[g][2][q] + sLw[g][3][q];
        Lpart[row * 4 + h] = L;
      }
    }
  }
}

// ---------------------------------------------------------------------------
// Fused attn-split combine + LayerNorm(h + O/L) * g + b, BOTH graphs.
// ---------------------------------------------------------------------------
__global__ __launch_bounds__(256) void ln_combine_dual(
    const float* __restrict__ hm, const float* __restrict__ Om,
    const float* __restrict__ Lm, const float* __restrict__ gm,
    const float* __restrict__ bm, float* __restrict__ outm,
    const float* __restrict__ hp, const float* __restrict__ Op,
    const float* __restrict__ Lp, const float* __restrict__ gp,
    const float* __restrict__ bp, float* __restrict__ outp)
{
  int idx = blockIdx.x * 256 + threadIdx.x;
  const float *hb, *Opart, *Lpart, *g, *bb;
  float* out;
  int N;
  int totalM = NMC * 64;
  if (idx < totalM) {
    hb = hm; Opart = Om; Lpart = Lm; g = gm; bb = bm; out = outm; N = NMC;
  } else {
    idx -= totalM;
    if (idx >= NPC * 64) return;
    hb = hp; Opart = Op; Lpart = Lp; g = gp; bb = bp; out = outp; N = NPC;
  }
  int n = idx >> 6, d = idx & 63, h = d >> 4;
  float O = 0.f, L = 0.f;
  #pragma unroll
  for (int s = 0; s < NSPLIT; s++) {
    size_t row = (size_t)s * N + n;
    O += Opart[row * 64 + d];
    L += Lpart[row * 4 + h];
  }
  float v = hb[idx] + O / L;
  float sm = v;
  #pragma unroll
  for (int o = 1; o < 64; o <<= 1) sm += __shfl_xor(sm, o);
  float mu = sm * 0.015625f;
  float c = v - mu;
  float q = c * c;
  #pragma unroll
  for (int o = 1; o < 64; o <<= 1) q += __shfl_xor(q, o);
  float var = q * 0.015625f;
  out[idx] = c * rsqrtf(var + 1e-5f) * g[d] + bb[d];
}

// ---------------------------------------------------------------------------
// Pooling via sorted-run register accumulation.
// ---------------------------------------------------------------------------
__global__ __launch_bounds__(256) void pool_run_kernel(
    const float* __restrict__ xm, const int* __restrict__ bm,
    const float* __restrict__ xp, const int* __restrict__ bp,
    float* __restrict__ sums, float* __restrict__ cnt)
{
  int wid = (blockIdx.x * 256 + threadIdx.x) >> 6;
  int lane = threadIdx.x & 63;
  const float* x;
  const int* batch;
  int n0, colOff, cntOff;
  if (wid < 64) {
    x = xm; batch = bm; n0 = wid * 64; colOff = 0; cntOff = 0;
  } else {
    wid -= 64;
    if (wid >= 128) return;
    x = xp; batch = bp; n0 = wid * 64; colOff = 64; cntOff = 32;
  }
  float acc = 0.f;
  int cur = batch[n0];
  int run = 0;
  for (int i = 0; i < 64; i++) {
    int n = n0 + i;
    int s = batch[n];
    if (s != cur) {
      atomicAdd(&sums[cur * 128 + colOff + lane], acc);
      if (lane == 0) atomicAdd(&cnt[cntOff + cur], (float)run);
      acc = 0.f; run = 0; cur = s;
    }
    acc += x[(size_t)n * 64 + lane];
    run++;
  }
  atomicAdd(&sums[cur * 128 + colOff + lane], acc);
  if (lane == 0) atomicAdd(&cnt[cntOff + cur], (float)run);
}

// ---------------------------------------------------------------------------
// final head
// ---------------------------------------------------------------------------
__global__ __launch_bounds__(256) void final_kernel(
    const float* __restrict__ sums, const float* __restrict__ cnt,
    const float* __restrict__ fc1w, const float* __restrict__ fc1b,
    const float* __restrict__ fc2w, const float* __restrict__ fc2b,
    float* __restrict__ out)
{
  __shared__ float z[32 * 128];
  __shared__ float h1[32 * 64];
  int t = threadIdx.x;
  for (int f = t; f < 32 * 128; f += 256) {
    int s = f >> 7, j = f & 127;
    float c = cnt[(j >> 6) * 32 + s];
    z[f] = sums[f] / fmaxf(c, 1.f);
  }
  __syncthreads();
  for (int f = t; f < 32 * 64; f += 256) {
    int s = f >> 6, o = f & 63;
    float acc = fc1b[o];
    for (int j = 0; j < 128; j++) acc += z[s * 128 + j] * fc1w[j * 64 + o];
    h1[f] = fmaxf(acc, 0.f);
  }
  __syncthreads();
  if (t < 32) {
    float acc = fc2b[0];
    for (int o = 0; o < 64; o++) acc += h1[t * 64 + o] * fc2w[o];
    out[t] = 1.f / (1.f + __expf(-acc));
  }
}

// ---------------------------------------------------------------------------
extern "C" void kernel_launch(void* const* d_in, const int* in_sizes, int n_in,
                              void* d_out, int out_size, void* d_ws, size_t ws_size,
                              hipStream_t stream)
{
  (void)in_sizes; (void)n_in; (void)out_size; (void)ws_size;
  const float* mol_x          = (const float*)d_in[0];
  const float* prot_x         = (const float*)d_in[1];
  const float* mol_edge_attr  = (const float*)d_in[2];
  const float* prot_edge_attr = (const float*)d_in[3];
  const float* inm_w = (const float*)d_in[4];
  const float* inm_b = (const float*)d_in[5];
  const float* inp_w = (const float*)d_in[6];
  const float* inp_b = (const float*)d_in[7];
  const float* iem_w = (const float*)d_in[8];
  const float* iem_b = (const float*)d_in[9];
  const float* iep_w = (const float*)d_in[10];
  const float* iep_b = (const float*)d_in[11];
  const float* gm_w1 = (const float*)d_in[12];
  const float* gm_b1 = (const float*)d_in[13];
  const float* gm_w2 = (const float*)d_in[14];
  const float* gm_b2 = (const float*)d_in[15];
  const float* gp_w1 = (const float*)d_in[16];
  const float* gp_b1 = (const float*)d_in[17];
  const float* gp_w2 = (const float*)d_in[18];
  const float* gp_b2 = (const float*)d_in[19];
  const float* m2p_w = (const float*)d_in[20];
  const float* m2p_b = (const float*)d_in[21];
  const float* p2m_w = (const float*)d_in[22];
  const float* p2m_b = (const float*)d_in[23];
  const float* lnm_g = (const float*)d_in[24];
  const float* lnm_b = (const float*)d_in[25];
  const float* lnp_g = (const float*)d_in[26];
  const float* lnp_b = (const float*)d_in[27];
  const float* fc1_w = (const float*)d_in[28];
  const float* fc1_b = (const float*)d_in[29];
  const float* fc2_w = (const float*)d_in[30];
  const float* fc2_b = (const float*)d_in[31];
  const int* mol_ei     = (const int*)d_in[32];
  const int* prot_ei    = (const int*)d_in[33];
  const int* mol_batch  = (const int*)d_in[34];
  const int* prot_batch = (const int*)d_in[35];

  const int NM = NMC, NP = NPC;

  float* ws = (float*)d_ws;
  size_t off = 0;
  auto nxt  = [&](size_t n) { float* p = ws + off; off += n; return p; };
  auto nxtH = [&](size_t n) { _Float16* p = (_Float16*)(ws + off); off += (n + 1) / 2; return p; };
  auto nxtI = [&](size_t n) { int* p = (int*)(ws + off); off += n; return p; };
  float* x_mol    = nxt((size_t)NM * 64);
  float* x_prot   = nxt((size_t)NP * 64);
  float* agg_mol  = nxt((size_t)NM * 64);
  float* agg_prot = nxt((size_t)NP * 64);
  float* h_mol    = nxt((size_t)NM * 64);
  float* h_prot   = nxt((size_t)NP * 64);
  _Float16* Qm  = nxtH((size_t)NM * 64);
  _Float16* Km  = nxtH((size_t)NM * 64);
  _Float16* Vtm = nxtH((size_t)NM * 64);
  _Float16* Qp  = nxtH((size_t)NP * 64);
  _Float16* Kp  = nxtH((size_t)NP * 64);
  _Float16* Vtp = nxtH((size_t)NP * 64);
  float* OPm = nxt((size_t)NSPLIT * NM * 64);
  float* LPm = nxt((size_t)NSPLIT * NM * 4);
  float* OPp = nxt((size_t)NSPLIT * NP * 64);
  float* LPp = nxt((size_t)NSPLIT * NP * 4);
  float* pool = nxt(32 * 128);
  float* cnt  = nxt(64);
  int* deg      = nxtI(NTOT);        // zeroed below
  int* rowStart = nxtI(NTOT + 1);
  int* cursor   = nxtI(NTOT);
  int* eidPerm  = nxtI(ETOT);
  int* srcPerm  = nxtI(ETOT);
  _Float16* eaPerm = nxtH((size_t)ETOT * 64);

  // ---- CSR + edge-embedding setup (once per call) ----
  (void)hipMemsetAsync(deg, 0, NTOT * 4, stream);
  deg_hist_kernel<<<(ETOT + 255) / 256, 256, 0, stream>>>(mol_ei, prot_ei, deg);
  scan_kernel<<<1, 256, 0, stream>>>(deg, rowStart, cursor);
  fill_kernel<<<(ETOT + 255) / 256, 256, 0, stream>>>(mol_ei, prot_ei, cursor, eidPerm, srcPerm);
  ea_perm_kernel<<<ETOT / 4, 256, 0, stream>>>(eidPerm,
      mol_edge_attr, iem_w, iem_b, prot_edge_attr, iep_w, iep_b, eaPerm);

  init_embed_kernel<<<NM * 64 / 256, 256, 0, stream>>>(mol_x, inm_w, inm_b, x_mol, NM, 11);
  init_embed_kernel<<<NP * 64 / 256, 256, 0, stream>>>(prot_x, inp_w, inp_b, x_prot, NP, 15);

  for (int l = 0; l < 3; l++) {
    gine_gather_kernel<<<NTOT / 4, 256, 0, stream>>>(x_mol, x_prot, rowStart, srcPerm,
                                                     eaPerm, agg_mol, agg_prot);
    gine_mlp_dual<<<192, 256, 0, stream>>>(
        x_mol, agg_mol, gm_w1 + l * 4096, gm_b1 + l * 64, gm_w2 + l * 4096, gm_b2 + l * 64, h_mol,
        x_prot, agg_prot, gp_w1 + l * 4096, gp_b1 + l * 64, gp_w2 + l * 4096, gp_b2 + l * 64, h_prot);
    // m2p: Q=mol (m2p W0), K/V=prot (m2p W1,W2); p2m: Q=prot (p2m W0), K/V=mol (p2m W1,W2)
    proj_qkv_dual<<<192, 256, 0, stream>>>(
        h_mol,
        m2p_w + (l * 3 + 0) * 4096, m2p_b + (l * 3 + 0) * 64,
        p2m_w + (l * 3 + 1) * 4096, p2m_b + (l * 3 + 1) * 64,
        p2m_w + (l * 3 + 2) * 4096, p2m_b + (l * 3 + 2) * 64,
        Qm, Km, Vtm,
        h_prot,
        p2m_w + (l * 3 + 0) * 4096, p2m_b + (l * 3 + 0) * 64,
        m2p_w + (l * 3 + 1) * 4096, m2p_b + (l * 3 + 1) * 64,
        m2p_w + (l * 3 + 2) * 4096, m2p_b + (l * 3 + 2) * 64,
        Qp, Kp, Vtp);
    attn_split_kernel<<<dim3(96, 4, NSPLIT), 256, 0, stream>>>(
        Qm, Kp, Vtp, OPm, LPm, Qp, Km, Vtm, OPp, LPp);
    ln_combine_dual<<<(NM + NP) * 64 / 256, 256, 0, stream>>>(
        h_mol, OPm, LPm, lnm_g + l * 64, lnm_b + l * 64, x_mol,
        h_prot, OPp, LPp, lnp_g + l * 64, lnp_b + l * 64, x_prot);
  }

  (void)hipMemsetAsync(pool, 0, (32 * 128 + 64) * 4, stream);
  pool_run_kernel<<<48, 256, 0, stream>>>(x_mol, mol_batch, x_prot, prot_batch, pool, cnt);
  final_kernel<<<1, 256, 0, stream>>>(pool, cnt, fc1_w, fc1_b, fc2_w, fc2_b, (float*)d_out);
}

// Round 10
// 675.175 us; speedup vs baseline: 1.2616x; 1.1535x over previous
//
#include <hip/hip_runtime.h>
#include <cstddef>

typedef _Float16 f16x4 __attribute__((ext_vector_type(4)));
typedef __fp16 h16x2 __attribute__((ext_vector_type(2)));
typedef float f32x4 __attribute__((ext_vector_type(4)));

__device__ __forceinline__ f32x4 mfma16(f16x4 a, f16x4 b, f32x4 c) {
  return __builtin_amdgcn_mfma_f32_16x16x16f16(a, b, c, 0, 0, 0);
}

// raw v_exp_f32 (2^x). OCML exp2f wraps it in denormal fixup we don't need
// (inputs clamped to <=14, outputs >= 2^-inf handled as flush-to-zero fine).
__device__ __forceinline__ float fast_exp2(float x) {
#if __has_builtin(__builtin_amdgcn_exp2f)
  return __builtin_amdgcn_exp2f(x);
#else
  return exp2f(x);
#endif
}

// Q is pre-scaled by 0.25 * log2(e) so softmax weights are exp2(score).
#define QSCALE (0.25f * 1.44269504f)
#define NSPLIT 8
#define NMC 4096
#define NPC 8192
#define EMC 65536
#define EPC 262144
#define NTOT (NMC + NPC)      // 12288 combined nodes (prot offset by NMC)
#define ETOT (EMC + EPC)      // 327680 combined edges

// ---------------------------------------------------------------------------
// init node embedding, both graphs: out[n][o] = b[o] + sum_k in[n][k]*W[k][o]
// ---------------------------------------------------------------------------
__global__ __launch_bounds__(256) void init_embed_dual(
    const float* __restrict__ inm, const float* __restrict__ Wm,
    const float* __restrict__ bm, float* __restrict__ outm,
    const float* __restrict__ inp, const float* __restrict__ Wp,
    const float* __restrict__ bp, float* __restrict__ outp)
{
  int idx = blockIdx.x * 256 + threadIdx.x;
  const float *in, *W, *bb;
  float* out;
  int Kin;
  if (idx < NMC * 64) {
    in = inm; W = Wm; bb = bm; out = outm; Kin = 11;
  } else {
    idx -= NMC * 64;
    if (idx >= NPC * 64) return;
    in = inp; W = Wp; bb = bp; out = outp; Kin = 15;
  }
  int n = idx >> 6, o = idx & 63;
  float acc = bb[o];
  const float* row = in + (size_t)n * Kin;
  for (int k = 0; k < Kin; k++) acc += row[k] * W[k * 64 + o];
  out[idx] = acc;
}

// ===========================================================================
// CSR construction (once per call). Combined node space: mol [0,NM),
// prot [NM, NM+NP).
// ===========================================================================
__global__ __launch_bounds__(256) void deg_hist_kernel(
    const int* __restrict__ eim, const int* __restrict__ eip, int* __restrict__ deg)
{
  int idx = blockIdx.x * 256 + threadIdx.x;
  if (idx >= ETOT) return;
  int dst = (idx < EMC) ? eim[EMC + idx] : (eip[EPC + (idx - EMC)] + NMC);
  atomicAdd(&deg[dst], 1);
}

// one block, 256 threads, 48 elems each: exclusive scan of deg -> rowStart,
// cursor (working copy); rowStart[NTOT] = total.
__global__ __launch_bounds__(256) void scan_kernel(
    const int* __restrict__ deg, int* __restrict__ rowStart, int* __restrict__ cursor)
{
  __shared__ int part[256];
  int t = threadIdx.x;
  int base = t * 48;
  int local[48];
  int s = 0;
  #pragma unroll
  for (int i = 0; i < 48; i++) { local[i] = s; s += deg[base + i]; }
  part[t] = s;
  __syncthreads();
  #pragma unroll
  for (int d = 1; d < 256; d <<= 1) {
    int v = (t >= d) ? part[t - d] : 0;
    __syncthreads();
    part[t] += v;
    __syncthreads();
  }
  int prefix = (t == 0) ? 0 : part[t - 1];
  #pragma unroll
  for (int i = 0; i < 48; i++) {
    int v = prefix + local[i];
    rowStart[base + i] = v;
    cursor[base + i] = v;
  }
  if (t == 255) rowStart[NTOT] = prefix + s;
}

__global__ __launch_bounds__(256) void fill_kernel(
    const int* __restrict__ eim, const int* __restrict__ eip,
    int* __restrict__ cursor, int* __restrict__ eidPerm, int* __restrict__ srcPerm)
{
  int idx = blockIdx.x * 256 + threadIdx.x;
  if (idx >= ETOT) return;
  int e, src, dst;
  if (idx < EMC) {
    e = idx; src = eim[e]; dst = eim[EMC + e];
  } else {
    e = idx - EMC; src = eip[e]; dst = eip[EPC + e] + NMC;
  }
  int slot = atomicAdd(&cursor[dst], 1);
  eidPerm[slot] = e;
  srcPerm[slot] = src;
}

// layer-invariant edge embedding, materialized in slot order (fp16).
__global__ __launch_bounds__(256) void ea_perm_kernel(
    const int* __restrict__ eidPerm,
    const float* __restrict__ attrm, const float* __restrict__ Wem, const float* __restrict__ bem,
    const float* __restrict__ attrp, const float* __restrict__ Wep, const float* __restrict__ bep,
    _Float16* __restrict__ eaPerm)
{
  int wid = (blockIdx.x * 256 + threadIdx.x) >> 6;
  int lane = threadIdx.x & 63;
  if (wid >= ETOT) return;
  int e = eidPerm[wid];
  const float* arow;
  const float* We;
  const float* be;
  if (wid < EMC) { arow = attrm + (size_t)e * 10; We = Wem; be = bem; }
  else           { arow = attrp + (size_t)e * 10; We = Wep; be = bep; }
  float ea = be[lane];
  #pragma unroll
  for (int k = 0; k < 10; k++) ea += arow[k] * We[k * 64 + lane];
  eaPerm[(size_t)wid * 64 + lane] = (_Float16)ea;
}

// ---------------------------------------------------------------------------
// GINE aggregation via CSR gather: one wave per node, lane = dim.
// ---------------------------------------------------------------------------
__global__ __launch_bounds__(256) void gine_gather_kernel(
    const float* __restrict__ xm, const float* __restrict__ xp,
    const int* __restrict__ rowStart, const int* __restrict__ srcPerm,
    const _Float16* __restrict__ eaPerm,
    float* __restrict__ aggm, float* __restrict__ aggp)
{
  int n = (blockIdx.x * 256 + threadIdx.x) >> 6;
  int lane = threadIdx.x & 63;
  if (n >= NTOT) return;
  const float* x;
  float* agg;
  int nl;
  if (n < NMC) { x = xm; agg = aggm; nl = n; }
  else         { x = xp; agg = aggp; nl = n - NMC; }
  int b0 = rowStart[n], b1 = rowStart[n + 1];
  float acc = 0.f;
  int i = b0;
  for (; i + 3 < b1; i += 4) {
    int s0 = srcPerm[i], s1 = srcPerm[i + 1], s2 = srcPerm[i + 2], s3 = srcPerm[i + 3];
    float e0 = (float)eaPerm[(size_t)i * 64 + lane];
    float e1 = (float)eaPerm[(size_t)(i + 1) * 64 + lane];
    float e2 = (float)eaPerm[(size_t)(i + 2) * 64 + lane];
    float e3 = (float)eaPerm[(size_t)(i + 3) * 64 + lane];
    float x0 = x[(size_t)s0 * 64 + lane];
    float x1 = x[(size_t)s1 * 64 + lane];
    float x2 = x[(size_t)s2 * 64 + lane];
    float x3 = x[(size_t)s3 * 64 + lane];
    acc += fmaxf(x0 + e0, 0.f) + fmaxf(x1 + e1, 0.f)
         + fmaxf(x2 + e2, 0.f) + fmaxf(x3 + e3, 0.f);
  }
  for (; i < b1; i++) {
    int src = srcPerm[i];
    float m = x[(size_t)src * 64 + lane] + (float)eaPerm[(size_t)i * 64 + lane];
    acc += fmaxf(m, 0.f);
  }
  agg[(size_t)nl * 64 + lane] = acc;
}

// ---------------------------------------------------------------------------
// Fused GINE node MLP + QKV projection, both graphs. Per 64-node tile:
//   sBuf = x+agg -> hidden(W1,relu) -> h(W2,relu; written to global for the
//   LN residual and kept in LDS) -> Q,K (fp16 [h][n][16]) and Vt (fp16
//   [h][16][N]) with a single reused 16KB weight buffer.
// blocks [0,64) mol, [64,192) prot.
// ---------------------------------------------------------------------------
__global__ __launch_bounds__(256) void mlp_proj_dual(
    const float* __restrict__ xm, const float* __restrict__ aggm,
    const float* __restrict__ W1m, const float* __restrict__ B1m,
    const float* __restrict__ W2m, const float* __restrict__ B2m,
    float* __restrict__ hm,
    const float* __restrict__ Wqm, const float* __restrict__ bqm,
    const float* __restrict__ Wkm, const float* __restrict__ bkm,
    const float* __restrict__ Wvm, const float* __restrict__ bvm,
    _Float16* __restrict__ Qom, _Float16* __restrict__ Kom, _Float16* __restrict__ Vtom,
    const float* __restrict__ xp, const float* __restrict__ aggp,
    const float* __restrict__ W1p, const float* __restrict__ B1p,
    const float* __restrict__ W2p, const float* __restrict__ B2p,
    float* __restrict__ hp,
    const float* __restrict__ Wqp, const float* __restrict__ bqp,
    const float* __restrict__ Wkp, const float* __restrict__ bkp,
    const float* __restrict__ Wvp, const float* __restrict__ bvp,
    _Float16* __restrict__ Qop, _Float16* __restrict__ Kop, _Float16* __restrict__ Vtop)
{
  __shared__ __align__(16) float sW[64 * 64];
  __shared__ __align__(16) float sBuf[64 * 68];
  int t = threadIdx.x;
  int b = blockIdx.x;
  const float *x, *agg, *W1, *B1, *W2, *B2, *Wq, *bq, *Wk, *bk, *Wv, *bv;
  float* hg;
  _Float16 *Qo, *Ko, *Vto;
  int n0, N;
  if (b < 64) {
    x = xm; agg = aggm; W1 = W1m; B1 = B1m; W2 = W2m; B2 = B2m; hg = hm;
    Wq = Wqm; bq = bqm; Wk = Wkm; bk = bkm; Wv = Wvm; bv = bvm;
    Qo = Qom; Ko = Kom; Vto = Vtom; n0 = b * 64; N = NMC;
  } else {
    x = xp; agg = aggp; W1 = W1p; B1 = B1p; W2 = W2p; B2 = B2p; hg = hp;
    Wq = Wqp; bq = bqp; Wk = Wkp; bk = bkp; Wv = Wvp; bv = bvp;
    Qo = Qop; Ko = Kop; Vto = Vtop; n0 = (b - 64) * 64; N = NPC;
  }
  int n = t >> 2, kk = t & 3;
  float acc[16];

  // stage input tile + W1
  #pragma unroll
  for (int i = 0; i < 16; i++) {
    int f = t + i * 256;
    size_t g = (size_t)n0 * 64 + f;
    sBuf[(f >> 6) * 68 + (f & 63)] = x[g] + agg[g];
    sW[f] = W1[f];
  }
  __syncthreads();
  // hidden = relu(input @ W1 + B1)
  #pragma unroll
  for (int j = 0; j < 16; j++) acc[j] = B1[kk * 16 + j];
  #pragma unroll
  for (int d = 0; d < 64; d++) {
    float xv = sBuf[n * 68 + d];
    const float* wrow = &sW[d * 64 + kk * 16];
    #pragma unroll
    for (int j = 0; j < 16; j++) acc[j] += xv * wrow[j];
  }
  __syncthreads();
  #pragma unroll
  for (int j = 0; j < 16; j++) sBuf[n * 68 + kk * 16 + j] = fmaxf(acc[j], 0.f);
  #pragma unroll
  for (int i = 0; i < 16; i++) { int f = t + i * 256; sW[f] = W2[f]; }
  __syncthreads();
  // h = relu(hidden @ W2 + B2) ; write to global, then park in sBuf
  #pragma unroll
  for (int j = 0; j < 16; j++) acc[j] = B2[kk * 16 + j];
  #pragma unroll
  for (int d = 0; d < 64; d++) {
    float xv = sBuf[n * 68 + d];
    const float* wrow = &sW[d * 64 + kk * 16];
    #pragma unroll
    for (int j = 0; j < 16; j++) acc[j] += xv * wrow[j];
  }
  float* hop = hg + (size_t)(n0 + n) * 64 + kk * 16;
  #pragma unroll
  for (int j = 0; j < 16; j++) {
    acc[j] = fmaxf(acc[j], 0.f);
    hop[j] = acc[j];
  }
  __syncthreads();                       // hidden reads done -> safe overwrite
  #pragma unroll
  for (int j = 0; j < 16; j++) sBuf[n * 68 + kk * 16 + j] = acc[j];

  // Q, K, V projections from the h tile
  const float* Ws[3] = {Wq, Wk, Wv};
  const float* bs[3] = {bq, bk, bv};
  for (int p = 0; p < 3; p++) {
    if (p > 0) __syncthreads();          // previous sW reads done
    #pragma unroll
    for (int i = 0; i < 16; i++) { int f = t + i * 256; sW[f] = Ws[p][f]; }
    __syncthreads();
    #pragma unroll
    for (int j = 0; j < 16; j++) acc[j] = bs[p][kk * 16 + j];
    #pragma unroll
    for (int d = 0; d < 64; d++) {
      float xv = sBuf[n * 68 + d];
      const float* wrow = &sW[d * 64 + kk * 16];
      #pragma unroll
      for (int j = 0; j < 16; j++) acc[j] += xv * wrow[j];
    }
    if (p == 2) {
      #pragma unroll
      for (int j = 0; j < 16; j++)
        Vto[((size_t)kk * 16 + j) * N + (n0 + n)] = (_Float16)acc[j];
    } else {
      float scale = (p == 0) ? QSCALE : 1.0f;
      _Float16 tmp[16];
      #pragma unroll
      for (int j = 0; j < 16; j++) tmp[j] = (_Float16)(acc[j] * scale);
      _Float16* base = (p == 0) ? Qo : Ko;
      float4* dst = (float4*)(base + ((size_t)kk * N + n0 + n) * 16);
      dst[0] = ((float4*)tmp)[0];
      dst[1] = ((float4*)tmp)[1];
    }
  }
}

// ---------------------------------------------------------------------------
// Key-split MFMA cross-attention, both directions in one launch.
// Grid (96, H, NSPLIT): bx<32 -> m2p qblock, else p2m qblock. 128 queries
// per block; 4 waves own disjoint 64-key chunks of this block's key split.
// exp2 via raw v_exp_f32; packed cvt + fdot2 for P/L.
// ---------------------------------------------------------------------------
__global__ __launch_bounds__(256, 4) void attn_split_kernel(
    const _Float16* __restrict__ Qm, const _Float16* __restrict__ Kp,
    const _Float16* __restrict__ Vtp, float* __restrict__ OPm, float* __restrict__ LPm,
    const _Float16* __restrict__ Qp, const _Float16* __restrict__ Km,
    const _Float16* __restrict__ Vtm, float* __restrict__ OPp, float* __restrict__ LPp)
{
  const int bx = blockIdx.x;
  const _Float16 *Q, *K, *Vt;
  float *Opart, *Lpart;
  int Nq, Nk, qb;
  if (bx < 32) { Q = Qm; K = Kp; Vt = Vtp; Opart = OPm; Lpart = LPm; Nq = NMC; Nk = NPC; qb = bx; }
  else         { Q = Qp; K = Km; Vt = Vtm; Opart = OPp; Lpart = LPp; Nq = NPC; Nk = NMC; qb = bx - 32; }
  const int h = blockIdx.y;
  const int split = blockIdx.z;
  const int Ks = Nk / NSPLIT;
  const int q0 = qb * 128;
  const int t = threadIdx.x;
  const int wave = t >> 6, lane = t & 63;
  const int l16 = lane & 15, quad = lane >> 4;

  f16x4 qf[8];
  #pragma unroll
  for (int g = 0; g < 8; g++)
    qf[g] = *(const f16x4*)(Q + ((size_t)h * Nq + q0 + g * 16 + l16) * 16 + quad * 4);
  const _Float16* Kh = K + (size_t)h * Nk * 16;
  const _Float16* Vh = Vt + ((size_t)h * 16 + l16) * Nk;

  f32x4 oacc[8];
  float lacc[8];
  #pragma unroll
  for (int g = 0; g < 8; g++) { oacc[g] = (f32x4){0.f,0.f,0.f,0.f}; lacc[g] = 0.f; }
  const f32x4 zero = {0.f, 0.f, 0.f, 0.f};
  const h16x2 ones2 = {(__fp16)1.f, (__fp16)1.f};

  union PF { f16x4 v4; h16x2 h2[2]; };

  const int kend = (split + 1) * Ks;
  for (int kb = split * Ks + wave * 64; kb < kend; kb += 256) {
    f16x4 kf[4], vf[4];
    #pragma unroll
    for (int c = 0; c < 4; c++) {
      kf[c] = *(const f16x4*)(Kh + (size_t)(kb + c * 16 + l16) * 16 + quad * 4);
      vf[c] = *(const f16x4*)(Vh + kb + c * 16 + quad * 4);
    }
    #pragma unroll
    for (int g = 0; g < 8; g++) {
      f32x4 s[4];
      #pragma unroll
      for (int c = 0; c < 4; c++) s[c] = mfma16(kf[c], qf[g], zero);
      f16x4 pf[4];
      #pragma unroll
      for (int c = 0; c < 4; c++) {
        float p0 = fast_exp2(fminf(s[c][0], 14.f));
        float p1 = fast_exp2(fminf(s[c][1], 14.f));
        float p2 = fast_exp2(fminf(s[c][2], 14.f));
        float p3 = fast_exp2(fminf(s[c][3], 14.f));
        PF u;
        u.h2[0] = __builtin_amdgcn_cvt_pkrtz(p0, p1);
        u.h2[1] = __builtin_amdgcn_cvt_pkrtz(p2, p3);
        pf[c] = u.v4;
        lacc[g] = __builtin_amdgcn_fdot2(u.h2[0], ones2, lacc[g], false);
        lacc[g] = __builtin_amdgcn_fdot2(u.h2[1], ones2, lacc[g], false);
      }
      #pragma unroll
      for (int c = 0; c < 4; c++) oacc[g] = mfma16(vf[c], pf[c], oacc[g]);
    }
  }

  // quad-reduce L within wave: lane l16 then holds L[q] for this wave
  #pragma unroll
  for (int g = 0; g < 8; g++) {
    lacc[g] += __shfl_xor(lacc[g], 16);
    lacc[g] += __shfl_xor(lacc[g], 32);
  }

  // two-pass cross-wave combine (padded; ~20 KB)
  __shared__ float sO[4][4][16][17];   // [gg][wave][d][q(+pad)]
  __shared__ float sLw[8][4][16];      // [g][wave][q]
  if (quad == 0) {
    #pragma unroll
    for (int g = 0; g < 8; g++) sLw[g][wave][l16] = lacc[g];
  }
  int q = t >> 4, d = t & 15;
  #pragma unroll
  for (int pass = 0; pass < 2; pass++) {
    __syncthreads();
    #pragma unroll
    for (int gg = 0; gg < 4; gg++) {
      int g = pass * 4 + gg;
      #pragma unroll
      for (int r = 0; r < 4; r++) sO[gg][wave][quad * 4 + r][l16] = oacc[g][r];
    }
    __syncthreads();
    #pragma unroll
    for (int gg = 0; gg < 4; gg++) {
      int g = pass * 4 + gg;
      float O = 0.f;
      #pragma unroll
      for (int w = 0; w < 4; w++) O += sO[gg][w][d][q];
      size_t row = (size_t)split * Nq + q0 + g * 16 + q;
      Opart[row * 64 + h * 16 + d] = O;
      if (d == 0) {
        float L = sLw[g][0][q] + sLw[g][1][q] + sLw[g][2][q] + sLw[g][3][q];
        Lpart[row * 4 + h] = L;
      }
    }
  }
}

// ---------------------------------------------------------------------------
// Fused attn-split combine + LayerNorm(h + O/L) * g + b, BOTH graphs.
// ---------------------------------------------------------------------------
__global__ __launch_bounds__(256) void ln_combine_dual(
    const float* __restrict__ hm, const float* __restrict__ Om,
    const float* __restrict__ Lm, const float* __restrict__ gm,
    const float* __restrict__ bm, float* __restrict__ outm,
    const float* __restrict__ hp, const float* __restrict__ Op,
    const float* __restrict__ Lp, const float* __restrict__ gp,
    const float* __restrict__ bp, float* __restrict__ outp)
{
  int idx = blockIdx.x * 256 + threadIdx.x;
  const float *hb, *Opart, *Lpart, *g, *bb;
  float* out;
  int N;
  int totalM = NMC * 64;
  if (idx < totalM) {
    hb = hm; Opart = Om; Lpart = Lm; g = gm; bb = bm; out = outm; N = NMC;
  } else {
    idx -= totalM;
    if (idx >= NPC * 64) return;
    hb = hp; Opart = Op; Lpart = Lp; g = gp; bb = bp; out = outp; N = NPC;
  }
  int n = idx >> 6, d = idx & 63, h = d >> 4;
  float O = 0.f, L = 0.f;
  #pragma unroll
  for (int s = 0; s < NSPLIT; s++) {
    size_t row = (size_t)s * N + n;
    O += Opart[row * 64 + d];
    L += Lpart[row * 4 + h];
  }
  float v = hb[idx] + O / L;
  float sm = v;
  #pragma unroll
  for (int o = 1; o < 64; o <<= 1) sm += __shfl_xor(sm, o);
  float mu = sm * 0.015625f;
  float c = v - mu;
  float q = c * c;
  #pragma unroll
  for (int o = 1; o < 64; o <<= 1) q += __shfl_xor(q, o);
  float var = q * 0.015625f;
  out[idx] = c * rsqrtf(var + 1e-5f) * g[d] + bb[d];
}

// ---------------------------------------------------------------------------
// Pooling via sorted-run register accumulation.
// ---------------------------------------------------------------------------
__global__ __launch_bounds__(256) void pool_run_kernel(
    const float* __restrict__ xm, const int* __restrict__ bm,
    const float* __restrict__ xp, const int* __restrict__ bp,
    float* __restrict__ sums, float* __restrict__ cnt)
{
  int wid = (blockIdx.x * 256 + threadIdx.x) >> 6;
  int lane = threadIdx.x & 63;
  const float* x;
  const int* batch;
  int n0, colOff, cntOff;
  if (wid < 64) {
    x = xm; batch = bm; n0 = wid * 64; colOff = 0; cntOff = 0;
  } else {
    wid -= 64;
    if (wid >= 128) return;
    x = xp; batch = bp; n0 = wid * 64; colOff = 64; cntOff = 32;
  }
  float acc = 0.f;
  int cur = batch[n0];
  int run = 0;
  for (int i = 0; i < 64; i++) {
    int n = n0 + i;
    int s = batch[n];
    if (s != cur) {
      atomicAdd(&sums[cur * 128 + colOff + lane], acc);
      if (lane == 0) atomicAdd(&cnt[cntOff + cur], (float)run);
      acc = 0.f; run = 0; cur = s;
    }
    acc += x[(size_t)n * 64 + lane];
    run++;
  }
  atomicAdd(&sums[cur * 128 + colOff + lane], acc);
  if (lane == 0) atomicAdd(&cnt[cntOff + cur], (float)run);
}

// ---------------------------------------------------------------------------
// final head
// ---------------------------------------------------------------------------
__global__ __launch_bounds__(256) void final_kernel(
    const float* __restrict__ sums, const float* __restrict__ cnt,
    const float* __restrict__ fc1w, const float* __restrict__ fc1b,
    const float* __restrict__ fc2w, const float* __restrict__ fc2b,
    float* __restrict__ out)
{
  __shared__ float z[32 * 128];
  __shared__ float h1[32 * 64];
  int t = threadIdx.x;
  for (int f = t; f < 32 * 128; f += 256) {
    int s = f >> 7, j = f & 127;
    float c = cnt[(j >> 6) * 32 + s];
    z[f] = sums[f] / fmaxf(c, 1.f);
  }
  __syncthreads();
  for (int f = t; f < 32 * 64; f += 256) {
    int s = f >> 6, o = f & 63;
    float acc = fc1b[o];
    for (int j = 0; j < 128; j++) acc += z[s * 128 + j] * fc1w[j * 64 + o];
    h1[f] = fmaxf(acc, 0.f);
  }
  __syncthreads();
  if (t < 32) {
    float acc = fc2b[0];
    for (int o = 0; o < 64; o++) acc += h1[t * 64 + o] * fc2w[o];
    out[t] = 1.f / (1.f + __expf(-acc));
  }
}

// ---------------------------------------------------------------------------
extern "C" void kernel_launch(void* const* d_in, const int* in_sizes, int n_in,
                              void* d_out, int out_size, void* d_ws, size_t ws_size,
                              hipStream_t stream)
{
  (void)in_sizes; (void)n_in; (void)out_size; (void)ws_size;
  const float* mol_x          = (const float*)d_in[0];
  const float* prot_x         = (const float*)d_in[1];
  const float* mol_edge_attr  = (const float*)d_in[2];
  const float* prot_edge_attr = (const float*)d_in[3];
  const float* inm_w = (const float*)d_in[4];
  const float* inm_b = (const float*)d_in[5];
  const float* inp_w = (const float*)d_in[6];
  const float* inp_b = (const float*)d_in[7];
  const float* iem_w = (const float*)d_in[8];
  const float* iem_b = (const float*)d_in[9];
  const float* iep_w = (const float*)d_in[10];
  const float* iep_b = (const float*)d_in[11];
  const float* gm_w1 = (const float*)d_in[12];
  const float* gm_b1 = (const float*)d_in[13];
  const float* gm_w2 = (const float*)d_in[14];
  const float* gm_b2 = (const float*)d_in[15];
  const float* gp_w1 = (const float*)d_in[16];
  const float* gp_b1 = (const float*)d_in[17];
  const float* gp_w2 = (const float*)d_in[18];
  const float* gp_b2 = (const float*)d_in[19];
  const float* m2p_w = (const float*)d_in[20];
  const float* m2p_b = (const float*)d_in[21];
  const float* p2m_w = (const float*)d_in[22];
  const float* p2m_b = (const float*)d_in[23];
  const float* lnm_g = (const float*)d_in[24];
  const float* lnm_b = (const float*)d_in[25];
  const float* lnp_g = (const float*)d_in[26];
  const float* lnp_b = (const float*)d_in[27];
  const float* fc1_w = (const float*)d_in[28];
  const float* fc1_b = (const float*)d_in[29];
  const float* fc2_w = (const float*)d_in[30];
  const float* fc2_b = (const float*)d_in[31];
  const int* mol_ei     = (const int*)d_in[32];
  const int* prot_ei    = (const int*)d_in[33];
  const int* mol_batch  = (const int*)d_in[34];
  const int* prot_batch = (const int*)d_in[35];

  const int NM = NMC, NP = NPC;

  float* ws = (float*)d_ws;
  size_t off = 0;
  auto nxt  = [&](size_t n) { float* p = ws + off; off += n; return p; };
  auto nxtH = [&](size_t n) { _Float16* p = (_Float16*)(ws + off); off += (n + 1) / 2; return p; };
  auto nxtI = [&](size_t n) { int* p = (int*)(ws + off); off += n; return p; };
  float* x_mol    = nxt((size_t)NM * 64);
  float* x_prot   = nxt((size_t)NP * 64);
  float* agg_mol  = nxt((size_t)NM * 64);
  float* agg_prot = nxt((size_t)NP * 64);
  float* h_mol    = nxt((size_t)NM * 64);
  float* h_prot   = nxt((size_t)NP * 64);
  _Float16* Qm  = nxtH((size_t)NM * 64);
  _Float16* Km  = nxtH((size_t)NM * 64);
  _Float16* Vtm = nxtH((size_t)NM * 64);
  _Float16* Qp  = nxtH((size_t)NP * 64);
  _Float16* Kp  = nxtH((size_t)NP * 64);
  _Float16* Vtp = nxtH((size_t)NP * 64);
  float* OPm = nxt((size_t)NSPLIT * NM * 64);
  float* LPm = nxt((size_t)NSPLIT * NM * 4);
  float* OPp = nxt((size_t)NSPLIT * NP * 64);
  float* LPp = nxt((size_t)NSPLIT * NP * 4);
  float* pool = nxt(32 * 128);
  float* cnt  = nxt(64);
  int* deg      = nxtI(NTOT);        // zeroed below
  int* rowStart = nxtI(NTOT + 1);
  int* cursor   = nxtI(NTOT);
  int* eidPerm  = nxtI(ETOT);
  int* srcPerm  = nxtI(ETOT);
  _Float16* eaPerm = nxtH((size_t)ETOT * 64);

  // ---- CSR + edge-embedding setup (once per call) ----
  (void)hipMemsetAsync(deg, 0, NTOT * 4, stream);
  deg_hist_kernel<<<(ETOT + 255) / 256, 256, 0, stream>>>(mol_ei, prot_ei, deg);
  scan_kernel<<<1, 256, 0, stream>>>(deg, rowStart, cursor);
  fill_kernel<<<(ETOT + 255) / 256, 256, 0, stream>>>(mol_ei, prot_ei, cursor, eidPerm, srcPerm);
  ea_perm_kernel<<<ETOT / 4, 256, 0, stream>>>(eidPerm,
      mol_edge_attr, iem_w, iem_b, prot_edge_attr, iep_w, iep_b, eaPerm);

  init_embed_dual<<<(NM + NP) * 64 / 256, 256, 0, stream>>>(
      mol_x, inm_w, inm_b, x_mol, prot_x, inp_w, inp_b, x_prot);

  for (int l = 0; l < 3; l++) {
    gine_gather_kernel<<<NTOT / 4, 256, 0, stream>>>(x_mol, x_prot, rowStart, srcPerm,
                                                     eaPerm, agg_mol, agg_prot);
    // m2p: Q=mol (m2p W0), K/V=prot (m2p W1,W2); p2m: Q=prot (p2m W0), K/V=mol (p2m W1,W2)
    mlp_proj_dual<<<192, 256, 0, stream>>>(
        x_mol, agg_mol, gm_w1 + l * 4096, gm_b1 + l * 64, gm_w2 + l * 4096, gm_b2 + l * 64, h_mol,
        m2p_w + (l * 3 + 0) * 4096, m2p_b + (l * 3 + 0) * 64,
        p2m_w + (l * 3 + 1) * 4096, p2m_b + (l * 3 + 1) * 64,
        p2m_w + (l * 3 + 2) * 4096, p2m_b + (l * 3 + 2) * 64,
        Qm, Km, Vtm,
        x_prot, agg_prot, gp_w1 + l * 4096, gp_b1 + l * 64, gp_w2 + l * 4096, gp_b2 + l * 64, h_prot,
        p2m_w + (l * 3 + 0) * 4096, p2m_b + (l * 3 + 0) * 64,
        m2p_w + (l * 3 + 1) * 4096, m2p_b + (l * 3 + 1) * 64,
        m2p_w + (l * 3 + 2) * 4096, m2p_b + (l * 3 + 2) * 64,
        Qp, Kp, Vtp);
    attn_split_kernel<<<dim3(96, 4, NSPLIT), 256, 0, stream>>>(
        Qm, Kp, Vtp, OPm, LPm, Qp, Km, Vtm, OPp, LPp);
    ln_combine_dual<<<(NM + NP) * 64 / 256, 256, 0, stream>>>(
        h_mol, OPm, LPm, lnm_g + l * 64, lnm_b + l * 64, x_mol,
        h_prot, OPp, LPp, lnp_g + l * 64, lnp_b + l * 64, x_prot);
  }

  (void)hipMemsetAsync(pool, 0, (32 * 128 + 64) * 4, stream);
  pool_run_kernel<<<48, 256, 0, stream>>>(x_mol, mol_batch, x_prot, prot_batch, pool, cnt);
  final_kernel<<<1, 256, 0, stream>>>(pool, cnt, fc1_w, fc1_b, fc2_w, fc2_b, (float*)d_out);
}

// Round 11
// 659.757 us; speedup vs baseline: 1.2911x; 1.0234x over previous
//
#include <hip/hip_runtime.h>
#include <cstddef>

typedef _Float16 f16x4 __attribute__((ext_vector_type(4)));
typedef __fp16 h16x2 __attribute__((ext_vector_type(2)));
typedef float f32x4 __attribute__((ext_vector_type(4)));

__device__ __forceinline__ f32x4 mfma16(f16x4 a, f16x4 b, f32x4 c) {
  return __builtin_amdgcn_mfma_f32_16x16x16f16(a, b, c, 0, 0, 0);
}

// raw v_exp_f32 (2^x). OCML exp2f wraps it in denormal fixup we don't need.
__device__ __forceinline__ float fast_exp2(float x) {
#if __has_builtin(__builtin_amdgcn_exp2f)
  return __builtin_amdgcn_exp2f(x);
#else
  return exp2f(x);
#endif
}

// Q is pre-scaled by 0.25 * log2(e) so softmax weights are exp2(score).
#define QSCALE (0.25f * 1.44269504f)
#define NSPLIT 8
#define NMC 4096
#define NPC 8192
#define EMC 65536
#define EPC 262144
#define NTOT (NMC + NPC)      // 12288 combined nodes (prot offset by NMC)
#define ETOT (EMC + EPC)      // 327680 combined edges

// ---------------------------------------------------------------------------
// init node embedding, both graphs: out[n][o] = b[o] + sum_k in[n][k]*W[k][o]
// ---------------------------------------------------------------------------
__global__ __launch_bounds__(256) void init_embed_dual(
    const float* __restrict__ inm, const float* __restrict__ Wm,
    const float* __restrict__ bm, float* __restrict__ outm,
    const float* __restrict__ inp, const float* __restrict__ Wp,
    const float* __restrict__ bp, float* __restrict__ outp)
{
  int idx = blockIdx.x * 256 + threadIdx.x;
  const float *in, *W, *bb;
  float* out;
  int Kin;
  if (idx < NMC * 64) {
    in = inm; W = Wm; bb = bm; out = outm; Kin = 11;
  } else {
    idx -= NMC * 64;
    if (idx >= NPC * 64) return;
    in = inp; W = Wp; bb = bp; out = outp; Kin = 15;
  }
  int n = idx >> 6, o = idx & 63;
  float acc = bb[o];
  const float* row = in + (size_t)n * Kin;
  for (int k = 0; k < Kin; k++) acc += row[k] * W[k * 64 + o];
  out[idx] = acc;
}

// ===========================================================================
// CSR construction (once per call). Combined node space: mol [0,NM),
// prot [NM, NM+NP).
// ===========================================================================
__global__ __launch_bounds__(256) void deg_hist_kernel(
    const int* __restrict__ eim, const int* __restrict__ eip, int* __restrict__ deg)
{
  int idx = blockIdx.x * 256 + threadIdx.x;
  if (idx >= ETOT) return;
  int dst = (idx < EMC) ? eim[EMC + idx] : (eip[EPC + (idx - EMC)] + NMC);
  atomicAdd(&deg[dst], 1);
}

// one block, 256 threads, 48 elems each: exclusive scan of deg -> rowStart,
// cursor (working copy); rowStart[NTOT] = total.
__global__ __launch_bounds__(256) void scan_kernel(
    const int* __restrict__ deg, int* __restrict__ rowStart, int* __restrict__ cursor)
{
  __shared__ int part[256];
  int t = threadIdx.x;
  int base = t * 48;
  int local[48];
  int s = 0;
  #pragma unroll
  for (int i = 0; i < 48; i++) { local[i] = s; s += deg[base + i]; }
  part[t] = s;
  __syncthreads();
  #pragma unroll
  for (int d = 1; d < 256; d <<= 1) {
    int v = (t >= d) ? part[t - d] : 0;
    __syncthreads();
    part[t] += v;
    __syncthreads();
  }
  int prefix = (t == 0) ? 0 : part[t - 1];
  #pragma unroll
  for (int i = 0; i < 48; i++) {
    int v = prefix + local[i];
    rowStart[base + i] = v;
    cursor[base + i] = v;
  }
  if (t == 255) rowStart[NTOT] = prefix + s;
}

// fill CSR slots; also records slotOf[combined edge idx] for edge-order
// streaming in ea_perm.
__global__ __launch_bounds__(256) void fill_kernel(
    const int* __restrict__ eim, const int* __restrict__ eip,
    int* __restrict__ cursor, int* __restrict__ srcPerm, int* __restrict__ slotOf)
{
  int idx = blockIdx.x * 256 + threadIdx.x;
  if (idx >= ETOT) return;
  int src, dst;
  if (idx < EMC) {
    src = eim[idx]; dst = eim[EMC + idx];
  } else {
    int e = idx - EMC; src = eip[e]; dst = eip[EPC + e] + NMC;
  }
  int slot = atomicAdd(&cursor[dst], 1);
  srcPerm[slot] = src;
  slotOf[idx] = slot;
}

// layer-invariant edge embedding. EDGE-ORDER iteration: consecutive waves
// read consecutive 40B attr rows (coalesced streaming); the 128B embedding
// row is scatter-written to its CSR slot (writes don't stall the wave).
__global__ __launch_bounds__(256) void ea_perm_kernel(
    const int* __restrict__ slotOf,
    const float* __restrict__ attrm, const float* __restrict__ Wem, const float* __restrict__ bem,
    const float* __restrict__ attrp, const float* __restrict__ Wep, const float* __restrict__ bep,
    _Float16* __restrict__ eaPerm)
{
  int wid = (blockIdx.x * 256 + threadIdx.x) >> 6;   // combined edge idx
  int lane = threadIdx.x & 63;
  if (wid >= ETOT) return;
  const float* arow;
  const float* We;
  const float* be;
  if (wid < EMC) { arow = attrm + (size_t)wid * 10;        We = Wem; be = bem; }
  else           { arow = attrp + (size_t)(wid - EMC) * 10; We = Wep; be = bep; }
  float ea = be[lane];
  #pragma unroll
  for (int k = 0; k < 10; k++) ea += arow[k] * We[k * 64 + lane];
  int slot = slotOf[wid];
  eaPerm[(size_t)slot * 64 + lane] = (_Float16)ea;
}

// ---------------------------------------------------------------------------
// GINE aggregation via CSR gather: one wave per node, lane = dim.
// ---------------------------------------------------------------------------
__global__ __launch_bounds__(256) void gine_gather_kernel(
    const float* __restrict__ xm, const float* __restrict__ xp,
    const int* __restrict__ rowStart, const int* __restrict__ srcPerm,
    const _Float16* __restrict__ eaPerm,
    float* __restrict__ aggm, float* __restrict__ aggp)
{
  int n = (blockIdx.x * 256 + threadIdx.x) >> 6;
  int lane = threadIdx.x & 63;
  if (n >= NTOT) return;
  const float* x;
  float* agg;
  int nl;
  if (n < NMC) { x = xm; agg = aggm; nl = n; }
  else         { x = xp; agg = aggp; nl = n - NMC; }
  int b0 = rowStart[n], b1 = rowStart[n + 1];
  float acc = 0.f;
  int i = b0;
  for (; i + 3 < b1; i += 4) {
    int s0 = srcPerm[i], s1 = srcPerm[i + 1], s2 = srcPerm[i + 2], s3 = srcPerm[i + 3];
    float e0 = (float)eaPerm[(size_t)i * 64 + lane];
    float e1 = (float)eaPerm[(size_t)(i + 1) * 64 + lane];
    float e2 = (float)eaPerm[(size_t)(i + 2) * 64 + lane];
    float e3 = (float)eaPerm[(size_t)(i + 3) * 64 + lane];
    float x0 = x[(size_t)s0 * 64 + lane];
    float x1 = x[(size_t)s1 * 64 + lane];
    float x2 = x[(size_t)s2 * 64 + lane];
    float x3 = x[(size_t)s3 * 64 + lane];
    acc += fmaxf(x0 + e0, 0.f) + fmaxf(x1 + e1, 0.f)
         + fmaxf(x2 + e2, 0.f) + fmaxf(x3 + e3, 0.f);
  }
  for (; i < b1; i++) {
    int src = srcPerm[i];
    float m = x[(size_t)src * 64 + lane] + (float)eaPerm[(size_t)i * 64 + lane];
    acc += fmaxf(m, 0.f);
  }
  agg[(size_t)nl * 64 + lane] = acc;
}

// ---------------------------------------------------------------------------
// Fused GINE node MLP + QKV projection, both graphs.
// blocks [0,64) mol, [64,192) prot.
// ---------------------------------------------------------------------------
__global__ __launch_bounds__(256) void mlp_proj_dual(
    const float* __restrict__ xm, const float* __restrict__ aggm,
    const float* __restrict__ W1m, const float* __restrict__ B1m,
    const float* __restrict__ W2m, const float* __restrict__ B2m,
    float* __restrict__ hm,
    const float* __restrict__ Wqm, const float* __restrict__ bqm,
    const float* __restrict__ Wkm, const float* __restrict__ bkm,
    const float* __restrict__ Wvm, const float* __restrict__ bvm,
    _Float16* __restrict__ Qom, _Float16* __restrict__ Kom, _Float16* __restrict__ Vtom,
    const float* __restrict__ xp, const float* __restrict__ aggp,
    const float* __restrict__ W1p, const float* __restrict__ B1p,
    const float* __restrict__ W2p, const float* __restrict__ B2p,
    float* __restrict__ hp,
    const float* __restrict__ Wqp, const float* __restrict__ bqp,
    const float* __restrict__ Wkp, const float* __restrict__ bkp,
    const float* __restrict__ Wvp, const float* __restrict__ bvp,
    _Float16* __restrict__ Qop, _Float16* __restrict__ Kop, _Float16* __restrict__ Vtop)
{
  __shared__ __align__(16) float sW[64 * 64];
  __shared__ __align__(16) float sBuf[64 * 68];
  int t = threadIdx.x;
  int b = blockIdx.x;
  const float *x, *agg, *W1, *B1, *W2, *B2, *Wq, *bq, *Wk, *bk, *Wv, *bv;
  float* hg;
  _Float16 *Qo, *Ko, *Vto;
  int n0, N;
  if (b < 64) {
    x = xm; agg = aggm; W1 = W1m; B1 = B1m; W2 = W2m; B2 = B2m; hg = hm;
    Wq = Wqm; bq = bqm; Wk = Wkm; bk = bkm; Wv = Wvm; bv = bvm;
    Qo = Qom; Ko = Kom; Vto = Vtom; n0 = b * 64; N = NMC;
  } else {
    x = xp; agg = aggp; W1 = W1p; B1 = B1p; W2 = W2p; B2 = B2p; hg = hp;
    Wq = Wqp; bq = bqp; Wk = Wkp; bk = bkp; Wv = Wvp; bv = bvp;
    Qo = Qop; Ko = Kop; Vto = Vtop; n0 = (b - 64) * 64; N = NPC;
  }
  int n = t >> 2, kk = t & 3;
  float acc[16];

  // stage input tile + W1
  #pragma unroll
  for (int i = 0; i < 16; i++) {
    int f = t + i * 256;
    size_t g = (size_t)n0 * 64 + f;
    sBuf[(f >> 6) * 68 + (f & 63)] = x[g] + agg[g];
    sW[f] = W1[f];
  }
  __syncthreads();
  // hidden = relu(input @ W1 + B1)
  #pragma unroll
  for (int j = 0; j < 16; j++) acc[j] = B1[kk * 16 + j];
  #pragma unroll
  for (int d = 0; d < 64; d++) {
    float xv = sBuf[n * 68 + d];
    const float* wrow = &sW[d * 64 + kk * 16];
    #pragma unroll
    for (int j = 0; j < 16; j++) acc[j] += xv * wrow[j];
  }
  __syncthreads();
  #pragma unroll
  for (int j = 0; j < 16; j++) sBuf[n * 68 + kk * 16 + j] = fmaxf(acc[j], 0.f);
  #pragma unroll
  for (int i = 0; i < 16; i++) { int f = t + i * 256; sW[f] = W2[f]; }
  __syncthreads();
  // h = relu(hidden @ W2 + B2) ; write to global, then park in sBuf
  #pragma unroll
  for (int j = 0; j < 16; j++) acc[j] = B2[kk * 16 + j];
  #pragma unroll
  for (int d = 0; d < 64; d++) {
    float xv = sBuf[n * 68 + d];
    const float* wrow = &sW[d * 64 + kk * 16];
    #pragma unroll
    for (int j = 0; j < 16; j++) acc[j] += xv * wrow[j];
  }
  float* hop = hg + (size_t)(n0 + n) * 64 + kk * 16;
  #pragma unroll
  for (int j = 0; j < 16; j++) {
    acc[j] = fmaxf(acc[j], 0.f);
    hop[j] = acc[j];
  }
  __syncthreads();                       // hidden reads done -> safe overwrite
  #pragma unroll
  for (int j = 0; j < 16; j++) sBuf[n * 68 + kk * 16 + j] = acc[j];

  // Q, K, V projections from the h tile
  const float* Ws[3] = {Wq, Wk, Wv};
  const float* bs[3] = {bq, bk, bv};
  for (int p = 0; p < 3; p++) {
    if (p > 0) __syncthreads();          // previous sW reads done
    #pragma unroll
    for (int i = 0; i < 16; i++) { int f = t + i * 256; sW[f] = Ws[p][f]; }
    __syncthreads();
    #pragma unroll
    for (int j = 0; j < 16; j++) acc[j] = bs[p][kk * 16 + j];
    #pragma unroll
    for (int d = 0; d < 64; d++) {
      float xv = sBuf[n * 68 + d];
      const float* wrow = &sW[d * 64 + kk * 16];
      #pragma unroll
      for (int j = 0; j < 16; j++) acc[j] += xv * wrow[j];
    }
    if (p == 2) {
      #pragma unroll
      for (int j = 0; j < 16; j++)
        Vto[((size_t)kk * 16 + j) * N + (n0 + n)] = (_Float16)acc[j];
    } else {
      float scale = (p == 0) ? QSCALE : 1.0f;
      _Float16 tmp[16];
      #pragma unroll
      for (int j = 0; j < 16; j++) tmp[j] = (_Float16)(acc[j] * scale);
      _Float16* base = (p == 0) ? Qo : Ko;
      float4* dst = (float4*)(base + ((size_t)kk * N + n0 + n) * 16);
      dst[0] = ((float4*)tmp)[0];
      dst[1] = ((float4*)tmp)[1];
    }
  }
}

// ---------------------------------------------------------------------------
// Key-split MFMA cross-attention, both directions in one launch.
// ---------------------------------------------------------------------------
__global__ __launch_bounds__(256, 4) void attn_split_kernel(
    const _Float16* __restrict__ Qm, const _Float16* __restrict__ Kp,
    const _Float16* __restrict__ Vtp, float* __restrict__ OPm, float* __restrict__ LPm,
    const _Float16* __restrict__ Qp, const _Float16* __restrict__ Km,
    const _Float16* __restrict__ Vtm, float* __restrict__ OPp, float* __restrict__ LPp)
{
  const int bx = blockIdx.x;
  const _Float16 *Q, *K, *Vt;
  float *Opart, *Lpart;
  int Nq, Nk, qb;
  if (bx < 32) { Q = Qm; K = Kp; Vt = Vtp; Opart = OPm; Lpart = LPm; Nq = NMC; Nk = NPC; qb = bx; }
  else         { Q = Qp; K = Km; Vt = Vtm; Opart = OPp; Lpart = LPp; Nq = NPC; Nk = NMC; qb = bx - 32; }
  const int h = blockIdx.y;
  const int split = blockIdx.z;
  const int Ks = Nk / NSPLIT;
  const int q0 = qb * 128;
  const int t = threadIdx.x;
  const int wave = t >> 6, lane = t & 63;
  const int l16 = lane & 15, quad = lane >> 4;

  f16x4 qf[8];
  #pragma unroll
  for (int g = 0; g < 8; g++)
    qf[g] = *(const f16x4*)(Q + ((size_t)h * Nq + q0 + g * 16 + l16) * 16 + quad * 4);
  const _Float16* Kh = K + (size_t)h * Nk * 16;
  const _Float16* Vh = Vt + ((size_t)h * 16 + l16) * Nk;

  f32x4 oacc[8];
  float lacc[8];
  #pragma unroll
  for (int g = 0; g < 8; g++) { oacc[g] = (f32x4){0.f,0.f,0.f,0.f}; lacc[g] = 0.f; }
  const f32x4 zero = {0.f, 0.f, 0.f, 0.f};
  const h16x2 ones2 = {(__fp16)1.f, (__fp16)1.f};

  union PF { f16x4 v4; h16x2 h2[2]; };

  const int kend = (split + 1) * Ks;
  for (int kb = split * Ks + wave * 64; kb < kend; kb += 256) {
    f16x4 kf[4], vf[4];
    #pragma unroll
    for (int c = 0; c < 4; c++) {
      kf[c] = *(const f16x4*)(Kh + (size_t)(kb + c * 16 + l16) * 16 + quad * 4);
      vf[c] = *(const f16x4*)(Vh + kb + c * 16 + quad * 4);
    }
    #pragma unroll
    for (int g = 0; g < 8; g++) {
      f32x4 s[4];
      #pragma unroll
      for (int c = 0; c < 4; c++) s[c] = mfma16(kf[c], qf[g], zero);
      f16x4 pf[4];
      #pragma unroll
      for (int c = 0; c < 4; c++) {
        float p0 = fast_exp2(fminf(s[c][0], 14.f));
        float p1 = fast_exp2(fminf(s[c][1], 14.f));
        float p2 = fast_exp2(fminf(s[c][2], 14.f));
        float p3 = fast_exp2(fminf(s[c][3], 14.f));
        PF u;
        u.h2[0] = __builtin_amdgcn_cvt_pkrtz(p0, p1);
        u.h2[1] = __builtin_amdgcn_cvt_pkrtz(p2, p3);
        pf[c] = u.v4;
        lacc[g] = __builtin_amdgcn_fdot2(u.h2[0], ones2, lacc[g], false);
        lacc[g] = __builtin_amdgcn_fdot2(u.h2[1], ones2, lacc[g], false);
      }
      #pragma unroll
      for (int c = 0; c < 4; c++) oacc[g] = mfma16(vf[c], pf[c], oacc[g]);
    }
  }

  // quad-reduce L within wave
  #pragma unroll
  for (int g = 0; g < 8; g++) {
    lacc[g] += __shfl_xor(lacc[g], 16);
    lacc[g] += __shfl_xor(lacc[g], 32);
  }

  // two-pass cross-wave combine (padded; ~20 KB)
  __shared__ float sO[4][4][16][17];   // [gg][wave][d][q(+pad)]
  __shared__ float sLw[8][4][16];      // [g][wave][q]
  if (quad == 0) {
    #pragma unroll
    for (int g = 0; g < 8; g++) sLw[g][wave][l16] = lacc[g];
  }
  int q = t >> 4, d = t & 15;
  #pragma unroll
  for (int pass = 0; pass < 2; pass++) {
    __syncthreads();
    #pragma unroll
    for (int gg = 0; gg < 4; gg++) {
      int g = pass * 4 + gg;
      #pragma unroll
      for (int r = 0; r < 4; r++) sO[gg][wave][quad * 4 + r][l16] = oacc[g][r];
    }
    __syncthreads();
    #pragma unroll
    for (int gg = 0; gg < 4; gg++) {
      int g = pass * 4 + gg;
      float O = 0.f;
      #pragma unroll
      for (int w = 0; w < 4; w++) O += sO[gg][w][d][q];
      size_t row = (size_t)split * Nq + q0 + g * 16 + q;
      Opart[row * 64 + h * 16 + d] = O;
      if (d == 0) {
        float L = sLw[g][0][q] + sLw[g][1][q] + sLw[g][2][q] + sLw[g][3][q];
        Lpart[row * 4 + h] = L;
      }
    }
  }
}

// ---------------------------------------------------------------------------
// Fused attn-split combine + LayerNorm(h + O/L) * g + b, BOTH graphs.
// ---------------------------------------------------------------------------
__global__ __launch_bounds__(256) void ln_combine_dual(
    const float* __restrict__ hm, const float* __restrict__ Om,
    const float* __restrict__ Lm, const float* __restrict__ gm,
    const float* __restrict__ bm, float* __restrict__ outm,
    const float* __restrict__ hp, const float* __restrict__ Op,
    const float* __restrict__ Lp, const float* __restrict__ gp,
    const float* __restrict__ bp, float* __restrict__ outp)
{
  int idx = blockIdx.x * 256 + threadIdx.x;
  const float *hb, *Opart, *Lpart, *g, *bb;
  float* out;
  int N;
  int totalM = NMC * 64;
  if (idx < totalM) {
    hb = hm; Opart = Om; Lpart = Lm; g = gm; bb = bm; out = outm; N = NMC;
  } else {
    idx -= totalM;
    if (idx >= NPC * 64) return;
    hb = hp; Opart = Op; Lpart = Lp; g = gp; bb = bp; out = outp; N = NPC;
  }
  int n = idx >> 6, d = idx & 63, h = d >> 4;
  float O = 0.f, L = 0.f;
  #pragma unroll
  for (int s = 0; s < NSPLIT; s++) {
    size_t row = (size_t)s * N + n;
    O += Opart[row * 64 + d];
    L += Lpart[row * 4 + h];
  }
  float v = hb[idx] + O / L;
  float sm = v;
  #pragma unroll
  for (int o = 1; o < 64; o <<= 1) sm += __shfl_xor(sm, o);
  float mu = sm * 0.015625f;
  float c = v - mu;
  float q = c * c;
  #pragma unroll
  for (int o = 1; o < 64; o <<= 1) q += __shfl_xor(q, o);
  float var = q * 0.015625f;
  out[idx] = c * rsqrtf(var + 1e-5f) * g[d] + bb[d];
}

// ---------------------------------------------------------------------------
// Pooling via sorted-run register accumulation.
// ---------------------------------------------------------------------------
__global__ __launch_bounds__(256) void pool_run_kernel(
    const float* __restrict__ xm, const int* __restrict__ bm,
    const float* __restrict__ xp, const int* __restrict__ bp,
    float* __restrict__ sums, float* __restrict__ cnt)
{
  int wid = (blockIdx.x * 256 + threadIdx.x) >> 6;
  int lane = threadIdx.x & 63;
  const float* x;
  const int* batch;
  int n0, colOff, cntOff;
  if (wid < 64) {
    x = xm; batch = bm; n0 = wid * 64; colOff = 0; cntOff = 0;
  } else {
    wid -= 64;
    if (wid >= 128) return;
    x = xp; batch = bp; n0 = wid * 64; colOff = 64; cntOff = 32;
  }
  float acc = 0.f;
  int cur = batch[n0];
  int run = 0;
  for (int i = 0; i < 64; i++) {
    int n = n0 + i;
    int s = batch[n];
    if (s != cur) {
      atomicAdd(&sums[cur * 128 + colOff + lane], acc);
      if (lane == 0) atomicAdd(&cnt[cntOff + cur], (float)run);
      acc = 0.f; run = 0; cur = s;
    }
    acc += x[(size_t)n * 64 + lane];
    run++;
  }
  atomicAdd(&sums[cur * 128 + colOff + lane], acc);
  if (lane == 0) atomicAdd(&cnt[cntOff + cur], (float)run);
}

// ---------------------------------------------------------------------------
// final head
// ---------------------------------------------------------------------------
__global__ __launch_bounds__(256) void final_kernel(
    const float* __restrict__ sums, const float* __restrict__ cnt,
    const float* __restrict__ fc1w, const float* __restrict__ fc1b,
    const float* __restrict__ fc2w, const float* __restrict__ fc2b,
    float* __restrict__ out)
{
  __shared__ float z[32 * 128];
  __shared__ float h1[32 * 64];
  int t = threadIdx.x;
  for (int f = t; f < 32 * 128; f += 256) {
    int s = f >> 7, j = f & 127;
    float c = cnt[(j >> 6) * 32 + s];
    z[f] = sums[f] / fmaxf(c, 1.f);
  }
  __syncthreads();
  for (int f = t; f < 32 * 64; f += 256) {
    int s = f >> 6, o = f & 63;
    float acc = fc1b[o];
    for (int j = 0; j < 128; j++) acc += z[s * 128 + j] * fc1w[j * 64 + o];
    h1[f] = fmaxf(acc, 0.f);
  }
  __syncthreads();
  if (t < 32) {
    float acc = fc2b[0];
    for (int o = 0; o < 64; o++) acc += h1[t * 64 + o] * fc2w[o];
    out[t] = 1.f / (1.f + __expf(-acc));
  }
}

// ---------------------------------------------------------------------------
extern "C" void kernel_launch(void* const* d_in, const int* in_sizes, int n_in,
                              void* d_out, int out_size, void* d_ws, size_t ws_size,
                              hipStream_t stream)
{
  (void)in_sizes; (void)n_in; (void)out_size; (void)ws_size;
  const float* mol_x          = (const float*)d_in[0];
  const float* prot_x         = (const float*)d_in[1];
  const float* mol_edge_attr  = (const float*)d_in[2];
  const float* prot_edge_attr = (const float*)d_in[3];
  const float* inm_w = (const float*)d_in[4];
  const float* inm_b = (const float*)d_in[5];
  const float* inp_w = (const float*)d_in[6];
  const float* inp_b = (const float*)d_in[7];
  const float* iem_w = (const float*)d_in[8];
  const float* iem_b = (const float*)d_in[9];
  const float* iep_w = (const float*)d_in[10];
  const float* iep_b = (const float*)d_in[11];
  const float* gm_w1 = (const float*)d_in[12];
  const float* gm_b1 = (const float*)d_in[13];
  const float* gm_w2 = (const float*)d_in[14];
  const float* gm_b2 = (const float*)d_in[15];
  const float* gp_w1 = (const float*)d_in[16];
  const float* gp_b1 = (const float*)d_in[17];
  const float* gp_w2 = (const float*)d_in[18];
  const float* gp_b2 = (const float*)d_in[19];
  const float* m2p_w = (const float*)d_in[20];
  const float* m2p_b = (const float*)d_in[21];
  const float* p2m_w = (const float*)d_in[22];
  const float* p2m_b = (const float*)d_in[23];
  const float* lnm_g = (const float*)d_in[24];
  const float* lnm_b = (const float*)d_in[25];
  const float* lnp_g = (const float*)d_in[26];
  const float* lnp_b = (const float*)d_in[27];
  const float* fc1_w = (const float*)d_in[28];
  const float* fc1_b = (const float*)d_in[29];
  const float* fc2_w = (const float*)d_in[30];
  const float* fc2_b = (const float*)d_in[31];
  const int* mol_ei     = (const int*)d_in[32];
  const int* prot_ei    = (const int*)d_in[33];
  const int* mol_batch  = (const int*)d_in[34];
  const int* prot_batch = (const int*)d_in[35];

  const int NM = NMC, NP = NPC;

  float* ws = (float*)d_ws;
  size_t off = 0;
  auto nxt  = [&](size_t n) { float* p = ws + off; off += n; return p; };
  auto nxtH = [&](size_t n) { _Float16* p = (_Float16*)(ws + off); off += (n + 1) / 2; return p; };
  auto nxtI = [&](size_t n) { int* p = (int*)(ws + off); off += n; return p; };
  float* x_mol    = nxt((size_t)NM * 64);
  float* x_prot   = nxt((size_t)NP * 64);
  float* agg_mol  = nxt((size_t)NM * 64);
  float* agg_prot = nxt((size_t)NP * 64);
  float* h_mol    = nxt((size_t)NM * 64);
  float* h_prot   = nxt((size_t)NP * 64);
  _Float16* Qm  = nxtH((size_t)NM * 64);
  _Float16* Km  = nxtH((size_t)NM * 64);
  _Float16* Vtm = nxtH((size_t)NM * 64);
  _Float16* Qp  = nxtH((size_t)NP * 64);
  _Float16* Kp  = nxtH((size_t)NP * 64);
  _Float16* Vtp = nxtH((size_t)NP * 64);
  float* OPm = nxt((size_t)NSPLIT * NM * 64);
  float* LPm = nxt((size_t)NSPLIT * NM * 4);
  float* OPp = nxt((size_t)NSPLIT * NP * 64);
  float* LPp = nxt((size_t)NSPLIT * NP * 4);
  float* pool = nxt(32 * 128);
  float* cnt  = nxt(64);
  int* deg      = nxtI(NTOT);        // zeroed below
  int* rowStart = nxtI(NTOT + 1);
  int* cursor   = nxtI(NTOT);
  int* slotOf   = nxtI(ETOT);
  int* srcPerm  = nxtI(ETOT);
  _Float16* eaPerm = nxtH((size_t)ETOT * 64);

  // ---- CSR + edge-embedding setup (once per call) ----
  (void)hipMemsetAsync(deg, 0, NTOT * 4, stream);
  deg_hist_kernel<<<(ETOT + 255) / 256, 256, 0, stream>>>(mol_ei, prot_ei, deg);
  scan_kernel<<<1, 256, 0, stream>>>(deg, rowStart, cursor);
  fill_kernel<<<(ETOT + 255) / 256, 256, 0, stream>>>(mol_ei, prot_ei, cursor, srcPerm, slotOf);
  ea_perm_kernel<<<ETOT / 4, 256, 0, stream>>>(slotOf,
      mol_edge_attr, iem_w, iem_b, prot_edge_attr, iep_w, iep_b, eaPerm);

  init_embed_dual<<<(NM + NP) * 64 / 256, 256, 0, stream>>>(
      mol_x, inm_w, inm_b, x_mol, prot_x, inp_w, inp_b, x_prot);

  for (int l = 0; l < 3; l++) {
    gine_gather_kernel<<<NTOT / 4, 256, 0, stream>>>(x_mol, x_prot, rowStart, srcPerm,
                                                     eaPerm, agg_mol, agg_prot);
    // m2p: Q=mol (m2p W0), K/V=prot (m2p W1,W2); p2m: Q=prot (p2m W0), K/V=mol (p2m W1,W2)
    mlp_proj_dual<<<192, 256, 0, stream>>>(
        x_mol, agg_mol, gm_w1 + l * 4096, gm_b1 + l * 64, gm_w2 + l * 4096, gm_b2 + l * 64, h_mol,
        m2p_w + (l * 3 + 0) * 4096, m2p_b + (l * 3 + 0) * 64,
        p2m_w + (l * 3 + 1) * 4096, p2m_b + (l * 3 + 1) * 64,
        p2m_w + (l * 3 + 2) * 4096, p2m_b + (l * 3 + 2) * 64,
        Qm, Km, Vtm,
        x_prot, agg_prot, gp_w1 + l * 4096, gp_b1 + l * 64, gp_w2 + l * 4096, gp_b2 + l * 64, h_prot,
        p2m_w + (l * 3 + 0) * 4096, p2m_b + (l * 3 + 0) * 64,
        m2p_w + (l * 3 + 1) * 4096, m2p_b + (l * 3 + 1) * 64,
        m2p_w + (l * 3 + 2) * 4096, m2p_b + (l * 3 + 2) * 64,
        Qp, Kp, Vtp);
    attn_split_kernel<<<dim3(96, 4, NSPLIT), 256, 0, stream>>>(
        Qm, Kp, Vtp, OPm, LPm, Qp, Km, Vtm, OPp, LPp);
    ln_combine_dual<<<(NM + NP) * 64 / 256, 256, 0, stream>>>(
        h_mol, OPm, LPm, lnm_g + l * 64, lnm_b + l * 64, x_mol,
        h_prot, OPp, LPp, lnp_g + l * 64, lnp_b + l * 64, x_prot);
  }

  (void)hipMemsetAsync(pool, 0, (32 * 128 + 64) * 4, stream);
  pool_run_kernel<<<48, 256, 0, stream>>>(x_mol, mol_batch, x_prot, prot_batch, pool, cnt);
  final_kernel<<<1, 256, 0, stream>>>(pool, cnt, fc1_w, fc1_b, fc2_w, fc2_b, (float*)d_out);
}